// Round 1
// baseline (5468.342 us; speedup 1.0000x reference)
//
#include <hip/hip_runtime.h>
#include <math.h>

#define DEV __device__ __forceinline__

DEV float fexp(float x){ return __expf(x); }
DEV float elu_(float x){ return x > 0.f ? x : fexp(x) - 1.f; }
DEV float sigm_(float x){ return 1.f/(1.f + fexp(-x)); }
DEV float tanh_(float x){ float e = fexp(2.f*x); return 1.f - 2.f/(e + 1.f); }

// ---------------------------------------------------------------------------
// init: stack=0, p=[1,0..], mem=0, c_prev=tile(c_0), softmax of module op-weights
// ---------------------------------------------------------------------------
__global__ __launch_bounds__(256)
void init_k(const float* __restrict__ c0, const float* __restrict__ c3ow,
            const float* __restrict__ c4ow, const float* __restrict__ aow,
            float* __restrict__ stack, float* __restrict__ pvec,
            float* __restrict__ mem, float* __restrict__ cprev,
            float* __restrict__ swb)
{
  int idx = blockIdx.x*256 + threadIdx.x;
  int stride = gridDim.x*256;
  for (int i = idx; i < 64*150*8; i += stride) stack[i] = 0.f;
  for (int i = idx; i < 64*8;    i += stride) pvec[i] = ((i & 7) == 0) ? 1.f : 0.f;
  for (int i = idx; i < 64*512;  i += stride) mem[i] = 0.f;
  for (int i = idx; i < 64*512;  i += stride) cprev[i] = c0[i & 511];
  if (idx < 8) {
    const float* ow = (idx < 4) ? (c3ow + idx*6)
                    : (idx < 6) ? (c4ow + (idx-4)*6)
                                : (aow  + (idx-6)*6);
    float mx = ow[0];
    for (int m = 1; m < 6; ++m) mx = fmaxf(mx, ow[m]);
    float e[6]; float s = 0.f;
    for (int m = 0; m < 6; ++m) { e[m] = fexp(ow[m]-mx); s += e[m]; }
    for (int m = 0; m < 6; ++m) swb[idx*6+m] = e[m]/s;
  }
}

// ---------------------------------------------------------------------------
// batched tiled transpose: src[b][r][c] -> dst[b][c][r]
// ---------------------------------------------------------------------------
__global__ __launch_bounds__(256)
void transpose_k(const float* __restrict__ src, float* __restrict__ dst,
                 int rows, int cols)
{
  __shared__ float tile[32][33];
  const size_t base = (size_t)blockIdx.z * rows * cols;
  int c0 = blockIdx.x*32, r0 = blockIdx.y*32;
  int tx = threadIdx.x & 31, ty = threadIdx.x >> 5;
  for (int i = 0; i < 32; i += 8) {
    int r = r0+ty+i, c = c0+tx;
    if (r < rows && c < cols) tile[ty+i][tx] = src[base + (size_t)r*cols + c];
  }
  __syncthreads();
  for (int i = 0; i < 32; i += 8) {
    int c = c0+ty+i, r = r0+tx;
    if (c < cols && r < rows) dst[base + (size_t)c*rows + r] = tile[tx][ty+i];
  }
}

// ---------------------------------------------------------------------------
// generic row-GEMM: C[r][n] = act( sum_k A[r][k]*B[k][n] (+A2 concat seg) + bias[n] )
// A rows contiguous (stride == Kseg); optional row-gather (embedding lookup).
// RT rows x (256*CPT) cols per block, K staged in LDS chunks of 32.
// ---------------------------------------------------------------------------
template<int RT, int CPT>
__global__ __launch_bounds__(256)
void rowgemm_k(const float* __restrict__ A, const int* __restrict__ gather, int K1,
               const float* __restrict__ A2, int K2,
               const float* __restrict__ B, const float* __restrict__ bias,
               float* __restrict__ C, int R, int N, int act)
{
  const int tx = threadIdx.x;
  const int n0 = blockIdx.x * (256*CPT);
  const int r0 = blockIdx.y * RT;
  __shared__ __align__(16) float Ast[32][RT];
  float acc[RT][CPT];
#pragma unroll
  for (int r = 0; r < RT; ++r)
#pragma unroll
    for (int c = 0; c < CPT; ++c) acc[r][c] = 0.f;

  int nn[CPT]; bool nv[CPT];
#pragma unroll
  for (int c = 0; c < CPT; ++c) { nn[c] = n0 + tx + c*256; nv[c] = nn[c] < N; }

  for (int seg = 0; seg < 2; ++seg) {
    const float* As = seg ? A2 : A;
    const int Ks    = seg ? K2 : K1;
    const int kbase = seg ? K1 : 0;
    if (Ks <= 0) continue;  // uniform across block
    for (int kb = 0; kb < Ks; kb += 32) {
      const int klim = (Ks - kb < 32) ? (Ks - kb) : 32;
      __syncthreads();
      for (int e = tx; e < RT*32; e += 256) {
        int r = e >> 5, kk = e & 31;
        float v = 0.f;
        int rr = r0 + r;
        if (rr < R && kk < klim) {
          int arow = gather ? gather[rr] : rr;
          v = As[(size_t)arow*Ks + kb + kk];
        }
        Ast[kk][r] = v;
      }
      __syncthreads();
      const float* Brow = B + (size_t)(kbase + kb)*N;
      auto body = [&](int kk) {
        float av[RT];
#pragma unroll
        for (int r4 = 0; r4 < RT; r4 += 4) {
          float4 t4 = *(const float4*)&Ast[kk][r4];
          av[r4] = t4.x; av[r4+1] = t4.y; av[r4+2] = t4.z; av[r4+3] = t4.w;
        }
        float w[CPT];
#pragma unroll
        for (int c = 0; c < CPT; ++c) w[c] = nv[c] ? Brow[(size_t)kk*N + nn[c]] : 0.f;
#pragma unroll
        for (int r = 0; r < RT; ++r)
#pragma unroll
          for (int c = 0; c < CPT; ++c) acc[r][c] += av[r]*w[c];
      };
      if (klim == 32) {
#pragma unroll 8
        for (int kk = 0; kk < 32; ++kk) body(kk);
      } else {
        for (int kk = 0; kk < klim; ++kk) body(kk);
      }
    }
  }
#pragma unroll
  for (int r = 0; r < RT; ++r) {
    int rr = r0 + r; if (rr >= R) continue;
#pragma unroll
    for (int c = 0; c < CPT; ++c) {
      if (!nv[c]) continue;
      float v = acc[r][c] + (bias ? bias[nn[c]] : 0.f);
      if (act == 1) v = elu_(v);
      C[(size_t)rr*N + nn[c]] = v;
    }
  }
}

// ---------------------------------------------------------------------------
// bidirectional masked LSTM; block = (dir, 2 batches), recurrence in LDS.
// xW layout [b][s][1024]; lstm_out [b][s][512] (fwd 0:256 | bwd 256:512)
// ---------------------------------------------------------------------------
__global__ __launch_bounds__(1024)
void lstm_k(const float* __restrict__ xWf, const float* __restrict__ xWb,
            const float* __restrict__ Whf, const float* __restrict__ Whb,
            const int* __restrict__ qlen, float* __restrict__ lstm_out,
            float* __restrict__ qout)
{
  int dir = blockIdx.x >> 5;
  int b0  = (blockIdx.x & 31)*2;
  const float* xW = dir ? xWb : xWf;
  const float* Wh = dir ? Whb : Whf;
  __shared__ __align__(16) float hl[2][256];
  __shared__ __align__(16) float cl[2][256];
  __shared__ float zl[2][1024];
  int tid = threadIdx.x;
  if (tid < 512) { hl[tid>>8][tid&255] = 0.f; cl[tid>>8][tid&255] = 0.f; }
  int len0 = qlen[b0], len1 = qlen[b0+1];
  for (int ss = 0; ss < 30; ++ss) {
    int s = dir ? (29-ss) : ss;
    __syncthreads();           // h/c ready
    float z0 = xW[((size_t)b0*30 + s)*1024 + tid];
    float z1 = xW[((size_t)(b0+1)*30 + s)*1024 + tid];
#pragma unroll 4
    for (int k = 0; k < 256; k += 4) {
      float4 h0 = *(const float4*)&hl[0][k];
      float4 h1 = *(const float4*)&hl[1][k];
      float w0 = Wh[(size_t)(k+0)*1024 + tid];
      float w1 = Wh[(size_t)(k+1)*1024 + tid];
      float w2 = Wh[(size_t)(k+2)*1024 + tid];
      float w3 = Wh[(size_t)(k+3)*1024 + tid];
      z0 += h0.x*w0 + h0.y*w1 + h0.z*w2 + h0.w*w3;
      z1 += h1.x*w0 + h1.y*w1 + h1.z*w2 + h1.w*w3;
    }
    zl[0][tid] = z0; zl[1][tid] = z1;
    __syncthreads();
    if (tid < 512) {
      int g = tid>>8, u2 = tid&255, b = b0+g;
      float iv = zl[g][u2], fv = zl[g][256+u2], gv = zl[g][512+u2], ov = zl[g][768+u2];
      float cn = sigm_(fv)*cl[g][u2] + sigm_(iv)*tanh_(gv);
      float hn = sigm_(ov)*tanh_(cn);
      bool m = s < (g ? len1 : len0);
      lstm_out[((size_t)b*30 + s)*512 + dir*256 + u2] = m ? hn : 0.f;
      if (m) { hl[g][u2] = hn; cl[g][u2] = cn; }
    }
  }
  __syncthreads();
  if (tid < 512) {
    int g = tid>>8, u2 = tid&255;
    qout[(size_t)(b0+g)*512 + dir*256 + u2] = hl[g][u2];
  }
}

// ---------------------------------------------------------------------------
// wl = u @ Wmod; log_softmax -> w, entropy partial
// ---------------------------------------------------------------------------
__global__ __launch_bounds__(256)
void kc_k(const float* __restrict__ u, const float* __restrict__ Wmod,
          float* __restrict__ wout, float* __restrict__ imp_part, int t)
{
  int b = blockIdx.x;
  int lane = threadIdx.x & 63, wave = threadIdx.x >> 6;
  __shared__ float wl[9];
  for (int m = wave; m < 9; m += 4) {
    float acc = 0.f;
    for (int k = lane; k < 512; k += 64) acc += u[b*512+k]*Wmod[k*9+m];
#pragma unroll
    for (int off = 32; off; off >>= 1) acc += __shfl_down(acc, off);
    if (lane == 0) wl[m] = acc;
  }
  __syncthreads();
  if (threadIdx.x == 0) {
    float mx = wl[0];
    for (int m = 1; m < 9; ++m) mx = fmaxf(mx, wl[m]);
    float s = 0.f;
    for (int m = 0; m < 9; ++m) s += fexp(wl[m]-mx);
    float ls = logf(s);
    float ent = 0.f;
    for (int m = 0; m < 9; ++m) {
      float l = wl[m]-mx-ls;
      float w = fexp(l);
      wout[b*9+m] = w;
      ent -= w*l;
    }
    imp_part[t*64+b] = ent;
  }
}

// ---------------------------------------------------------------------------
// attention + context: scores over 30 steps -> softmax -> c (written to cprev)
// ---------------------------------------------------------------------------
__global__ __launch_bounds__(256)
void attn_k(const float* __restrict__ lstm_out, const float* __restrict__ u,
            const float* __restrict__ W3, float* __restrict__ cout)
{
  int b = blockIdx.x;
  int lane = threadIdx.x & 63, wave = threadIdx.x >> 6;
  __shared__ float sc[32];
  __shared__ float at[32];
  for (int s = wave; s < 30; s += 4) {
    float acc = 0.f;
    const float* lo = lstm_out + ((size_t)b*30 + s)*512;
    for (int h = lane; h < 512; h += 64) acc += lo[h]*u[b*512+h]*W3[h];
#pragma unroll
    for (int off = 32; off; off >>= 1) acc += __shfl_down(acc, off);
    if (lane == 0) sc[s] = acc;
  }
  __syncthreads();
  if (wave == 0) {
    float v = (lane < 30) ? sc[lane] : -3.4e38f;
    float mx = v;
#pragma unroll
    for (int off = 32; off; off >>= 1) mx = fmaxf(mx, __shfl_xor(mx, off));
    float e = (lane < 30) ? fexp(v-mx) : 0.f;
    float ssum = e;
#pragma unroll
    for (int off = 32; off; off >>= 1) ssum += __shfl_xor(ssum, off);
    if (lane < 30) at[lane] = e/ssum;
  }
  __syncthreads();
  for (int h = threadIdx.x; h < 512; h += 256) {
    float acc = 0.f;
#pragma unroll 6
    for (int s = 0; s < 30; ++s) acc += at[s]*lstm_out[((size_t)b*30 + s)*512 + h];
    cout[b*512+h] = acc;
  }
}

// ---------------------------------------------------------------------------
// p_dec, a_top = stack·p, a2 = stack·p_dec
// ---------------------------------------------------------------------------
__global__ __launch_bounds__(256)
void prep_k(const float* __restrict__ stack, const float* __restrict__ pvec,
            float* __restrict__ pdec, float* __restrict__ atop, float* __restrict__ a2)
{
  int b = blockIdx.x;
  float pv[8], pd[8];
#pragma unroll
  for (int l = 0; l < 8; ++l) pv[l] = pvec[b*8+l];
#pragma unroll
  for (int l = 0; l < 7; ++l) pd[l] = pv[l+1];
  pd[7] = 0.f; pd[0] += pv[0];
  if (threadIdx.x < 8) pdec[b*8+threadIdx.x] = pd[threadIdx.x];
  for (int p = threadIdx.x; p < 150; p += 256) {
    const float* st = stack + ((size_t)b*150 + p)*8;
    float s1 = 0.f, s2 = 0.f;
#pragma unroll
    for (int l = 0; l < 8; ++l) { float v = st[l]; s1 += v*pv[l]; s2 += v*pd[l]; }
    atop[b*150+p] = s1; a2[b*150+p] = s2;
  }
}

// ---------------------------------------------------------------------------
// cell modules: per (b,p) reduce over d of elu(c1*x+c0)*cw; outputs already
// weighted by module weights w -> S3 (mix3 m0..3), S45 (mix4 m0..1)
// ---------------------------------------------------------------------------
__global__ __launch_bounds__(256)
void modules_k(const float* __restrict__ imapT, const float* __restrict__ tmap,
               const float* __restrict__ atop, const float* __restrict__ a2,
               const float* __restrict__ swb, const float* __restrict__ c3w,
               const float* __restrict__ c3b, const float* __restrict__ c4w,
               const float* __restrict__ c4b, const float* __restrict__ wmod,
               float* __restrict__ s3, float* __restrict__ s45)
{
  int b = blockIdx.y;
  int lane = threadIdx.x & 63, wave = threadIdx.x >> 6;
  float W[6][6];
#pragma unroll
  for (int m = 0; m < 6; ++m)
#pragma unroll
    for (int i = 0; i < 6; ++i) W[m][i] = swb[m*6+i];
  for (int pi = 0; pi < 2; ++pi) {
    int p = blockIdx.x*8 + wave*2 + pi;
    if (p >= 150) continue;
    float a = atop[b*150+p], av2 = a2[b*150+p];
    float part[6] = {0,0,0,0,0,0};
    for (int d = lane; d < 512; d += 64) {
      float x = imapT[((size_t)b*150 + p)*512 + d];
      float t = tmap[b*512+d];
#pragma unroll
      for (int m = 0; m < 4; ++m) {
        float c1 = W[m][0]*t + W[m][1] + W[m][4] + (W[m][2] + W[m][3]*t)*a;
        float c0 = W[m][1]*t + W[m][5]*t*a;
        part[m] += elu_(c1*x + c0) * c3w[m*512+d];
      }
#pragma unroll
      for (int m = 0; m < 2; ++m) {
        float c1 = W[4+m][0]*t + W[4+m][1] + W[4+m][2]*a + W[4+m][3]*av2
                 + W[4+m][4]*a*av2 + W[4+m][5]*t*(a+av2);
        part[4+m] += elu_(c1*x + W[4+m][1]*t) * c4w[m*512+d];
      }
    }
#pragma unroll
    for (int m = 0; m < 6; ++m) {
#pragma unroll
      for (int off = 32; off; off >>= 1) part[m] += __shfl_down(part[m], off);
    }
    if (lane == 0) {
      const float* w = wmod + b*9;
      float r3  = w[0]*(part[0]+c3b[0]) + w[1]*(part[1]+c3b[1])
                + w[2]*(part[2]+c3b[2]) + w[3]*(part[3]+c3b[3]);
      float r45 = w[4]*(part[4]+c4b[0]) + w[5]*(part[5]+c4b[1]);
      s3[b*150+p] = r3; s45[b*150+p] = r45;
    }
  }
}

// ---------------------------------------------------------------------------
// ans modules: pooled6/7[b][d] = mean_p elu(mix)
// ---------------------------------------------------------------------------
__global__ __launch_bounds__(256)
void pooled_k(const float* __restrict__ imapT, const float* __restrict__ tmap,
              const float* __restrict__ atop, const float* __restrict__ a2,
              const float* __restrict__ swb,
              float* __restrict__ p6, float* __restrict__ p7)
{
  int b = blockIdx.x;
  float w6[6], w7[6];
#pragma unroll
  for (int i = 0; i < 6; ++i) { w6[i] = swb[36+i]; w7[i] = swb[42+i]; }
  for (int dd = 0; dd < 2; ++dd) {
    int d = threadIdx.x + dd*256;
    float t = tmap[b*512+d];
    float al = w6[0]*t + w6[1] + w6[4];
    float be = w6[2] + w6[3]*t;
    float ga = w6[1]*t;
    float de = w6[5]*t;
    float q0 = w7[0]*t + w7[1];
    float q5 = w7[5]*t;
    float c0b = w7[1]*t;
    float acc6 = 0.f, acc7 = 0.f;
    for (int p = 0; p < 150; ++p) {
      float x = imapT[((size_t)b*150 + p)*512 + d];
      float a = atop[b*150+p];
      float v2 = a2[b*150+p];
      acc6 += elu_((al + be*a)*x + ga + de*a);
      float c1 = q0 + w7[2]*a + w7[3]*v2 + w7[4]*a*v2 + q5*(a+v2);
      acc7 += elu_(c1*x + c0b);
    }
    p6[b*512+d] = acc6*(1.f/150.f);
    p7[b*512+d] = acc7*(1.f/150.f);
  }
}

// ---------------------------------------------------------------------------
// blended stack/p/mem update (9-way blend collapsed algebraically)
// ---------------------------------------------------------------------------
__global__ __launch_bounds__(256)
void update_k(const float* __restrict__ wmod, float* __restrict__ pvec,
              const float* __restrict__ pdec, float* __restrict__ stack,
              const float* __restrict__ s3, const float* __restrict__ s45,
              float* __restrict__ mem, const float* __restrict__ mem6,
              const float* __restrict__ mem7)
{
  int b = blockIdx.x;
  __shared__ float wsh[9], pls[8], pds[8];
  if (threadIdx.x < 9) wsh[threadIdx.x] = wmod[b*9+threadIdx.x];
  if (threadIdx.x < 8) {
    pls[threadIdx.x] = pvec[b*8+threadIdx.x];
    pds[threadIdx.x] = pdec[b*8+threadIdx.x];
  }
  __syncthreads();
  float W03 = wsh[0]+wsh[1]+wsh[2]+wsh[3];
  float W45 = wsh[4]+wsh[5];
  float WP = W03 + wsh[6] + wsh[8];
  float WD = W45 + wsh[7];
  for (int e = threadIdx.x; e < 1200; e += 256) {
    int p = e >> 3, l = e & 7;
    size_t idx = ((size_t)b*150 + p)*8 + l;
    float pl = pls[l], pdl = pds[l];
    stack[idx] = stack[idx]*(1.f - W03*pl - W45*pdl)
               + pl*s3[b*150+p] + pdl*s45[b*150+p];
  }
  float w6v = wsh[6], w7v = wsh[7];
  for (int d = threadIdx.x; d < 512; d += 256) {
    mem[b*512+d] = w6v*mem6[b*512+d] + w7v*mem7[b*512+d]
                 + (1.f - w6v - w7v)*mem[b*512+d];
  }
  __syncthreads();
  if (threadIdx.x < 8) pvec[b*8+threadIdx.x] = WP*pls[threadIdx.x] + WD*pds[threadIdx.x];
}

// ---------------------------------------------------------------------------
// imp_loss = sum of 576 per-(t,b) entropy partials
// ---------------------------------------------------------------------------
__global__ __launch_bounds__(256)
void imp_k(const float* __restrict__ part, float* __restrict__ out)
{
  int lane = threadIdx.x & 63, wave = threadIdx.x >> 6;
  float acc = 0.f;
  for (int i = threadIdx.x; i < 576; i += 256) acc += part[i];
#pragma unroll
  for (int off = 32; off; off >>= 1) acc += __shfl_down(acc, off);
  __shared__ float red[4];
  if (lane == 0) red[wave] = acc;
  __syncthreads();
  if (threadIdx.x == 0) out[0] = red[0]+red[1]+red[2]+red[3];
}

// ---------------------------------------------------------------------------
extern "C" void kernel_launch(void* const* d_in, const int* in_sizes, int n_in,
                              void* d_out, int out_size, void* d_ws, size_t ws_size,
                              hipStream_t stream)
{
  (void)in_sizes; (void)n_in; (void)out_size; (void)ws_size;
  const float* image = (const float*)d_in[0];
  const int*   ques  = (const int*)d_in[1];
  const int*   qlen  = (const int*)d_in[2];
  const float* embedW= (const float*)d_in[3];
  const float* Wi_f  = (const float*)d_in[4];
  const float* Wh_f  = (const float*)d_in[5];
  const float* b_f   = (const float*)d_in[6];
  const float* Wi_b  = (const float*)d_in[7];
  const float* Wh_b  = (const float*)d_in[8];
  const float* b_b   = (const float*)d_in[9];
  const float* W1    = (const float*)d_in[10];
  const float* b1    = (const float*)d_in[11];
  const float* W2w   = (const float*)d_in[12];
  const float* W2b   = (const float*)d_in[13];
  const float* W3    = (const float*)d_in[14];
  const float* c0    = (const float*)d_in[15];
  const float* Wmod  = (const float*)d_in[16];
  const float* ic1w  = (const float*)d_in[17];
  const float* ic1b  = (const float*)d_in[18];
  const float* ic2w  = (const float*)d_in[19];
  const float* ic2b  = (const float*)d_in[20];
  const float* i2mw  = (const float*)d_in[21];
  const float* i2mb  = (const float*)d_in[22];
  const float* t2mw  = (const float*)d_in[23];
  const float* t2mb  = (const float*)d_in[24];
  const float* c3ow  = (const float*)d_in[25];
  const float* c3cw  = (const float*)d_in[26];
  const float* c3cb  = (const float*)d_in[27];
  const float* c4ow  = (const float*)d_in[28];
  const float* c4cw  = (const float*)d_in[29];
  const float* c4cb  = (const float*)d_in[30];
  const float* aow   = (const float*)d_in[31];
  const float* ansW  = (const float*)d_in[32];
  const float* ansb  = (const float*)d_in[33];
  const float* o1w   = (const float*)d_in[34];
  const float* o1b   = (const float*)d_in[35];
  const float* o2w   = (const float*)d_in[36];
  const float* o2b   = (const float*)d_in[37];
  float* out = (float*)d_out;
  float* ws  = (float*)d_ws;

  size_t off = 0;
  auto alloc = [&](size_t n){ float* p = ws + off; off += n; return p; };
  float* imgT  = alloc(64ull*150*640);   // aliased as imapT after conv chain
  float* X1T   = alloc(64ull*150*512);
  float* X2T   = alloc(64ull*150*512);
  float* imapT = imgT;
  float* wT1   = alloc(640*512);
  float* wT2   = alloc(512*512);
  float* wT3   = alloc(512*512);
  float* xWfb  = alloc(64ull*30*1024);
  float* xWbb  = alloc(64ull*30*1024);
  float* lout  = alloc(64ull*30*512);
  float* qbuf  = alloc(64*512);
  float* stck  = alloc(64*150*8);
  float* pvec  = alloc(64*8);
  float* pdec  = alloc(64*8);
  float* memb  = alloc(64*512);
  float* cprev = alloc(64*512);
  float* tmp1  = alloc(64*512);
  float* ubuf  = alloc(64*512);
  float* wmw   = alloc(64*9);
  float* impp  = alloc(9*64);
  float* swb   = alloc(48);
  float* atop  = alloc(64*150);
  float* a2b   = alloc(64*150);
  float* s3b   = alloc(64*150);
  float* s45b  = alloc(64*150);
  float* p6b   = alloc(64*512);
  float* p7b   = alloc(64*512);
  float* m6b   = alloc(64*512);
  float* m7b   = alloc(64*512);
  float* tmapb = alloc(64*512);
  float* h1b   = alloc(64*1024);

  init_k<<<320, 256, 0, stream>>>(c0, c3ow, c4ow, aow, stck, pvec, memb, cprev, swb);
  transpose_k<<<dim3(5,20,64), 256, 0, stream>>>(image, imgT, 640, 150);
  transpose_k<<<dim3(20,16,1), 256, 0, stream>>>(ic1w, wT1, 512, 640);
  transpose_k<<<dim3(16,16,1), 256, 0, stream>>>(ic2w, wT2, 512, 512);
  transpose_k<<<dim3(16,16,1), 256, 0, stream>>>(i2mw, wT3, 512, 512);

  // embedding @ Wi (+bias) for both directions (gather fused)
  rowgemm_k<16,2><<<dim3(2,120), 256, 0, stream>>>(
      embedW, ques, 300, (const float*)nullptr, 0, Wi_f, b_f, xWfb, 1920, 1024, 0);
  rowgemm_k<16,2><<<dim3(2,120), 256, 0, stream>>>(
      embedW, ques, 300, (const float*)nullptr, 0, Wi_b, b_b, xWbb, 1920, 1024, 0);

  // conv chain (row-GEMM over 9600 (b,pixel) rows)
  rowgemm_k<16,2><<<dim3(1,600), 256, 0, stream>>>(
      imgT, (const int*)nullptr, 640, (const float*)nullptr, 0, wT1, ic1b, X1T, 9600, 512, 1);
  rowgemm_k<16,2><<<dim3(1,600), 256, 0, stream>>>(
      X1T, (const int*)nullptr, 512, (const float*)nullptr, 0, wT2, ic2b, X2T, 9600, 512, 0);
  rowgemm_k<16,2><<<dim3(1,600), 256, 0, stream>>>(
      X2T, (const int*)nullptr, 512, (const float*)nullptr, 0, wT3, i2mb, imapT, 9600, 512, 0);

  lstm_k<<<64, 1024, 0, stream>>>(xWfb, xWbb, Wh_f, Wh_b, qlen, lout, qbuf);

  for (int t = 0; t < 9; ++t) {
    rowgemm_k<4,1><<<dim3(2,16), 256, 0, stream>>>(
        qbuf, (const int*)nullptr, 512, (const float*)nullptr, 0,
        W1 + (size_t)t*512*512, b1, tmp1, 64, 512, 0);
    rowgemm_k<4,1><<<dim3(2,16), 256, 0, stream>>>(
        tmp1, (const int*)nullptr, 512, cprev, 512, W2w, W2b, ubuf, 64, 512, 0);
    kc_k<<<64, 256, 0, stream>>>(ubuf, Wmod, wmw, impp, t);
    attn_k<<<64, 256, 0, stream>>>(lout, ubuf, W3, cprev);
    rowgemm_k<4,1><<<dim3(2,16), 256, 0, stream>>>(
        cprev, (const int*)nullptr, 512, (const float*)nullptr, 0,
        t2mw, t2mb, tmapb, 64, 512, 0);
    prep_k<<<64, 256, 0, stream>>>(stck, pvec, pdec, atop, a2b);
    modules_k<<<dim3(19,64), 256, 0, stream>>>(
        imapT, tmapb, atop, a2b, swb, c3cw, c3cb, c4cw, c4cb, wmw, s3b, s45b);
    pooled_k<<<64, 256, 0, stream>>>(imapT, tmapb, atop, a2b, swb, p6b, p7b);
    rowgemm_k<4,1><<<dim3(2,16), 256, 0, stream>>>(
        p6b, (const int*)nullptr, 512, tmapb, 512, ansW, ansb, m6b, 64, 512, 0);
    rowgemm_k<4,1><<<dim3(2,16), 256, 0, stream>>>(
        p7b, (const int*)nullptr, 512, tmapb, 512, ansW + 524288, ansb + 512, m7b, 64, 512, 0);
    update_k<<<64, 256, 0, stream>>>(wmw, pvec, pdec, stck, s3b, s45b, memb, m6b, m7b);
  }

  rowgemm_k<4,1><<<dim3(4,16), 256, 0, stream>>>(
      qbuf, (const int*)nullptr, 512, memb, 512, o1w, o1b, h1b, 64, 1024, 1);
  rowgemm_k<4,1><<<dim3(1,16), 256, 0, stream>>>(
      h1b, (const int*)nullptr, 1024, (const float*)nullptr, 0, o2w, o2b, out, 64, 32, 0);
  imp_k<<<1, 256, 0, stream>>>(impp, out + 2048);
}

// Round 2
// 3360.744 us; speedup vs baseline: 1.6271x; 1.6271x over previous
//
#include <hip/hip_runtime.h>
#include <math.h>

#define DEV __device__ __forceinline__

DEV float fexp(float x){ return __expf(x); }
DEV float elu_(float x){ return x > 0.f ? x : fexp(x) - 1.f; }
DEV float sigm_(float x){ return 1.f/(1.f + fexp(-x)); }
DEV float tanh_(float x){ float e = fexp(2.f*x); return 1.f - 2.f/(e + 1.f); }
DEV unsigned bf16r(float x){ unsigned u = __float_as_uint(x);
  return (u + 0x7fffu + ((u>>16)&1u)) >> 16; }

// ---------------------------------------------------------------------------
// init: stack=0, p=[1,0..], mem=0, c_prev=tile(c_0), softmax of module op-weights
// ---------------------------------------------------------------------------
__global__ __launch_bounds__(256)
void init_k(const float* __restrict__ c0, const float* __restrict__ c3ow,
            const float* __restrict__ c4ow, const float* __restrict__ aow,
            float* __restrict__ stack, float* __restrict__ pvec,
            float* __restrict__ mem, float* __restrict__ cprev,
            float* __restrict__ swb)
{
  int idx = blockIdx.x*256 + threadIdx.x;
  int stride = gridDim.x*256;
  for (int i = idx; i < 64*150*8; i += stride) stack[i] = 0.f;
  for (int i = idx; i < 64*8;    i += stride) pvec[i] = ((i & 7) == 0) ? 1.f : 0.f;
  for (int i = idx; i < 64*512;  i += stride) mem[i] = 0.f;
  for (int i = idx; i < 64*512;  i += stride) cprev[i] = c0[i & 511];
  if (idx < 8) {
    const float* ow = (idx < 4) ? (c3ow + idx*6)
                    : (idx < 6) ? (c4ow + (idx-4)*6)
                                : (aow  + (idx-6)*6);
    float mx = ow[0];
    for (int m = 1; m < 6; ++m) mx = fmaxf(mx, ow[m]);
    float e[6]; float s = 0.f;
    for (int m = 0; m < 6; ++m) { e[m] = fexp(ow[m]-mx); s += e[m]; }
    for (int m = 0; m < 6; ++m) swb[idx*6+m] = e[m]/s;
  }
}

// ---------------------------------------------------------------------------
// pack Wh (both dirs) into bf16 pairs: whp[dir][k2][n] = bf16(Wh[2k2][n]) |
// bf16(Wh[2k2+1][n])<<16   (halves per-CU L2 traffic in the LSTM)
// ---------------------------------------------------------------------------
__global__ __launch_bounds__(256)
void pack_k(const float* __restrict__ Whf, const float* __restrict__ Whb,
            unsigned* __restrict__ whp)
{
  int idx = blockIdx.x*256 + threadIdx.x;      // 2*128*1024 total
  int dir = idx >> 17;
  int rem = idx & 131071;
  int k2  = rem >> 10;
  int n   = rem & 1023;
  const float* Wh = dir ? Whb : Whf;
  float lo = Wh[(size_t)(2*k2)*1024 + n];
  float hi = Wh[(size_t)(2*k2+1)*1024 + n];
  whp[idx] = bf16r(lo) | (bf16r(hi) << 16);
}

// ---------------------------------------------------------------------------
// batched tiled transpose: src[b][r][c] -> dst[b][c][r]
// ---------------------------------------------------------------------------
__global__ __launch_bounds__(256)
void transpose_k(const float* __restrict__ src, float* __restrict__ dst,
                 int rows, int cols)
{
  __shared__ float tile[32][33];
  const size_t base = (size_t)blockIdx.z * rows * cols;
  int c0 = blockIdx.x*32, r0 = blockIdx.y*32;
  int tx = threadIdx.x & 31, ty = threadIdx.x >> 5;
  for (int i = 0; i < 32; i += 8) {
    int r = r0+ty+i, c = c0+tx;
    if (r < rows && c < cols) tile[ty+i][tx] = src[base + (size_t)r*cols + c];
  }
  __syncthreads();
  for (int i = 0; i < 32; i += 8) {
    int c = c0+ty+i, r = r0+tx;
    if (c < cols && r < rows) dst[base + (size_t)c*rows + r] = tile[tx][ty+i];
  }
}

// ---------------------------------------------------------------------------
// generic row-GEMM (used for the big embed/conv GEMMs only)
// ---------------------------------------------------------------------------
template<int RT, int CPT>
__global__ __launch_bounds__(256)
void rowgemm_k(const float* __restrict__ A, const int* __restrict__ gather, int K1,
               const float* __restrict__ B, const float* __restrict__ bias,
               float* __restrict__ C, int R, int N, int act)
{
  const int tx = threadIdx.x;
  const int n0 = blockIdx.x * (256*CPT);
  const int r0 = blockIdx.y * RT;
  __shared__ __align__(16) float Ast[32][RT];
  float acc[RT][CPT];
#pragma unroll
  for (int r = 0; r < RT; ++r)
#pragma unroll
    for (int c = 0; c < CPT; ++c) acc[r][c] = 0.f;

  int nn[CPT]; bool nv[CPT];
#pragma unroll
  for (int c = 0; c < CPT; ++c) { nn[c] = n0 + tx + c*256; nv[c] = nn[c] < N; }

  for (int kb = 0; kb < K1; kb += 32) {
    const int klim = (K1 - kb < 32) ? (K1 - kb) : 32;
    __syncthreads();
    for (int e = tx; e < RT*32; e += 256) {
      int r = e >> 5, kk = e & 31;
      float v = 0.f;
      int rr = r0 + r;
      if (rr < R && kk < klim) {
        int arow = gather ? gather[rr] : rr;
        v = A[(size_t)arow*K1 + kb + kk];
      }
      Ast[kk][r] = v;
    }
    __syncthreads();
    const float* Brow = B + (size_t)kb*N;
    auto body = [&](int kk) {
      float av[RT];
#pragma unroll
      for (int r4 = 0; r4 < RT; r4 += 4) {
        float4 t4 = *(const float4*)&Ast[kk][r4];
        av[r4] = t4.x; av[r4+1] = t4.y; av[r4+2] = t4.z; av[r4+3] = t4.w;
      }
      float w[CPT];
#pragma unroll
      for (int c = 0; c < CPT; ++c) w[c] = nv[c] ? Brow[(size_t)kk*N + nn[c]] : 0.f;
#pragma unroll
      for (int r = 0; r < RT; ++r)
#pragma unroll
        for (int c = 0; c < CPT; ++c) acc[r][c] += av[r]*w[c];
    };
    if (klim == 32) {
#pragma unroll 8
      for (int kk = 0; kk < 32; ++kk) body(kk);
    } else {
      for (int kk = 0; kk < klim; ++kk) body(kk);
    }
  }
#pragma unroll
  for (int r = 0; r < RT; ++r) {
    int rr = r0 + r; if (rr >= R) continue;
#pragma unroll
    for (int c = 0; c < CPT; ++c) {
      if (!nv[c]) continue;
      float v = acc[r][c] + (bias ? bias[nn[c]] : 0.f);
      if (act == 1) v = elu_(v);
      C[(size_t)rr*N + nn[c]] = v;
    }
  }
}

// ---------------------------------------------------------------------------
// 64-row batch GEMM: C[64][N] = act( [A1|A2][64][K1+K2] @ B + bias )
// block: 512 thr = 8 waves; wave = 1 row; lane = 1 col of a 64-col tile.
// A tile staged once in LDS; K-loop is sync-free with coalesced B loads.
// z-dim indexes {A1,B,bias,C} by the given strides (multi-GEMM in 1 launch).
// ---------------------------------------------------------------------------
__global__ __launch_bounds__(512)
void gemm64_k(const float* __restrict__ A1, long zA1, int K1log,
              const float* __restrict__ A2, int K2,
              const float* __restrict__ B, long zB,
              const float* __restrict__ bias, int zbias,
              float* __restrict__ C, long zC, int N, int act)
{
  const int K1 = 1 << K1log;
  const int Kt = K1 + K2;
  __shared__ __align__(16) float As[8*1024];
  const int tid = threadIdx.x;
  const int z = blockIdx.z;
  const float* a1 = A1 + (size_t)z*zA1;

  for (int e = tid*4; e < 8*K1; e += 512*4) {
    int r = e >> K1log, j = e & (K1-1);
    *(float4*)&As[r*Kt + j] = *(const float4*)&a1[(size_t)(blockIdx.y*8 + r)*K1 + j];
  }
  if (K2 > 0) {
    for (int e = tid*4; e < 8*K2; e += 512*4) {
      int r = e >> 9, j = e & 511;   // K2 is always 512 when nonzero
      *(float4*)&As[r*Kt + K1 + j] = *(const float4*)&A2[(size_t)(blockIdx.y*8 + r)*512 + j];
    }
  }
  __syncthreads();

  const int n = blockIdx.x*64 + (tid & 63);
  const int wv = tid >> 6;
  const int rg = blockIdx.y*8 + wv;
  const bool nvalid = n < N;
  const float* Bp = B + (size_t)z*zB;
  float acc = 0.f;
#pragma unroll 8
  for (int k = 0; k < Kt; ++k) {
    float bv = nvalid ? Bp[(size_t)k*N + n] : 0.f;
    acc += As[wv*Kt + k] * bv;
  }
  if (nvalid) {
    float v = acc + (bias ? bias[(size_t)z*zbias + n] : 0.f);
    if (act == 1) v = elu_(v);
    C[(size_t)z*zC + (size_t)rg*N + n] = v;
  }
}

// ---------------------------------------------------------------------------
// bidirectional masked LSTM; block = (dir, 2 batches); Wh in packed bf16 pairs
// ---------------------------------------------------------------------------
__global__ __launch_bounds__(1024)
void lstm_k(const float* __restrict__ xWf, const float* __restrict__ xWb,
            const unsigned* __restrict__ whp,
            const int* __restrict__ qlen, float* __restrict__ lstm_out,
            float* __restrict__ qout)
{
  int dir = blockIdx.x >> 5;
  int b0  = (blockIdx.x & 31)*2;
  const float* xW = dir ? xWb : xWf;
  const unsigned* Wp = whp + (size_t)dir*131072;
  __shared__ __align__(16) float hl[2][256];
  __shared__ __align__(16) float cl[2][256];
  __shared__ float zl[2][1024];
  int tid = threadIdx.x;
  if (tid < 512) { hl[tid>>8][tid&255] = 0.f; cl[tid>>8][tid&255] = 0.f; }
  int len0 = qlen[b0], len1 = qlen[b0+1];
  for (int ss = 0; ss < 30; ++ss) {
    int s = dir ? (29-ss) : ss;
    __syncthreads();           // h/c ready
    float z0 = xW[((size_t)b0*30 + s)*1024 + tid];
    float z1 = xW[((size_t)(b0+1)*30 + s)*1024 + tid];
#pragma unroll 8
    for (int k2 = 0; k2 < 128; ++k2) {
      unsigned w01 = Wp[(size_t)k2*1024 + tid];
      float wlo = __uint_as_float(w01 << 16);
      float whi = __uint_as_float(w01 & 0xffff0000u);
      float2 h0 = *(const float2*)&hl[0][2*k2];
      float2 h1 = *(const float2*)&hl[1][2*k2];
      z0 += h0.x*wlo + h0.y*whi;
      z1 += h1.x*wlo + h1.y*whi;
    }
    zl[0][tid] = z0; zl[1][tid] = z1;
    __syncthreads();
    if (tid < 512) {
      int g = tid>>8, u2 = tid&255, b = b0+g;
      float iv = zl[g][u2], fv = zl[g][256+u2], gv = zl[g][512+u2], ov = zl[g][768+u2];
      float cn = sigm_(fv)*cl[g][u2] + sigm_(iv)*tanh_(gv);
      float hn = sigm_(ov)*tanh_(cn);
      bool m = s < (g ? len1 : len0);
      lstm_out[((size_t)b*30 + s)*512 + dir*256 + u2] = m ? hn : 0.f;
      if (m) { hl[g][u2] = hn; cl[g][u2] = cn; }
    }
  }
  __syncthreads();
  if (tid < 512) {
    int g = tid>>8, u2 = tid&255;
    qout[(size_t)(b0+g)*512 + dir*256 + u2] = hl[g][u2];
  }
}

// ---------------------------------------------------------------------------
// wl = u @ Wmod; log_softmax -> w, entropy partial
// ---------------------------------------------------------------------------
__global__ __launch_bounds__(256)
void kc_k(const float* __restrict__ u, const float* __restrict__ Wmod,
          float* __restrict__ wout, float* __restrict__ imp_part, int t)
{
  int b = blockIdx.x;
  int lane = threadIdx.x & 63, wave = threadIdx.x >> 6;
  __shared__ float wl[9];
  for (int m = wave; m < 9; m += 4) {
    float acc = 0.f;
    for (int k = lane; k < 512; k += 64) acc += u[b*512+k]*Wmod[k*9+m];
#pragma unroll
    for (int off = 32; off; off >>= 1) acc += __shfl_down(acc, off);
    if (lane == 0) wl[m] = acc;
  }
  __syncthreads();
  if (threadIdx.x == 0) {
    float mx = wl[0];
    for (int m = 1; m < 9; ++m) mx = fmaxf(mx, wl[m]);
    float s = 0.f;
    for (int m = 0; m < 9; ++m) s += fexp(wl[m]-mx);
    float ls = logf(s);
    float ent = 0.f;
    for (int m = 0; m < 9; ++m) {
      float l = wl[m]-mx-ls;
      float w = fexp(l);
      wout[b*9+m] = w;
      ent -= w*l;
    }
    imp_part[t*64+b] = ent;
  }
}

// ---------------------------------------------------------------------------
// attention + context -> cprev
// ---------------------------------------------------------------------------
__global__ __launch_bounds__(256)
void attn_k(const float* __restrict__ lstm_out, const float* __restrict__ u,
            const float* __restrict__ W3, float* __restrict__ cout)
{
  int b = blockIdx.x;
  int lane = threadIdx.x & 63, wave = threadIdx.x >> 6;
  __shared__ float sc[32];
  __shared__ float at[32];
  for (int s = wave; s < 30; s += 4) {
    float acc = 0.f;
    const float* lo = lstm_out + ((size_t)b*30 + s)*512;
    for (int h = lane; h < 512; h += 64) acc += lo[h]*u[b*512+h]*W3[h];
#pragma unroll
    for (int off = 32; off; off >>= 1) acc += __shfl_down(acc, off);
    if (lane == 0) sc[s] = acc;
  }
  __syncthreads();
  if (wave == 0) {
    float v = (lane < 30) ? sc[lane] : -3.4e38f;
    float mx = v;
#pragma unroll
    for (int off = 32; off; off >>= 1) mx = fmaxf(mx, __shfl_xor(mx, off));
    float e = (lane < 30) ? fexp(v-mx) : 0.f;
    float ssum = e;
#pragma unroll
    for (int off = 32; off; off >>= 1) ssum += __shfl_xor(ssum, off);
    if (lane < 30) at[lane] = e/ssum;
  }
  __syncthreads();
  for (int h = threadIdx.x; h < 512; h += 256) {
    float acc = 0.f;
#pragma unroll 6
    for (int s = 0; s < 30; ++s) acc += at[s]*lstm_out[((size_t)b*30 + s)*512 + h];
    cout[b*512+h] = acc;
  }
}

// ---------------------------------------------------------------------------
// fused modules + pooled: per (b, 8 p's) compute atop/a2 inline, the 6 cell
// module outputs (-> s3, s45) AND the ans-module elu sums (partials over p
// into part67[b][pb][2][512]).  imapT read once.
// ---------------------------------------------------------------------------
__global__ __launch_bounds__(256)
void modpool_k(const float* __restrict__ imapT, const float* __restrict__ tmap,
               const float* __restrict__ stack, const float* __restrict__ pvec,
               const float* __restrict__ swb, const float* __restrict__ c3w,
               const float* __restrict__ c3b, const float* __restrict__ c4w,
               const float* __restrict__ c4b, const float* __restrict__ wmod,
               float* __restrict__ s3, float* __restrict__ s45,
               float* __restrict__ part67)
{
  int b = blockIdx.y;
  int pb = blockIdx.x;
  int lane = threadIdx.x & 63, wave = threadIdx.x >> 6;
  __shared__ float pv[8], pd[8];
  __shared__ float wpart[4][2][512];
  if (threadIdx.x < 8) pv[threadIdx.x] = pvec[b*8+threadIdx.x];
  __syncthreads();
  if (threadIdx.x < 8) {
    int l = threadIdx.x;
    pd[l] = (l < 7 ? pv[l+1] : 0.f) + (l == 0 ? pv[0] : 0.f);
  }
  __syncthreads();

  float W[8][6];
#pragma unroll
  for (int m = 0; m < 8; ++m)
#pragma unroll
    for (int i = 0; i < 6; ++i) W[m][i] = swb[m*6+i];

  float acc6[8], acc7[8];
#pragma unroll
  for (int i = 0; i < 8; ++i) { acc6[i] = 0.f; acc7[i] = 0.f; }

  for (int pi = 0; pi < 2; ++pi) {
    int p = pb*8 + wave*2 + pi;
    if (p >= 150) continue;
    const float* st = stack + ((size_t)b*150 + p)*8;
    float a = 0.f, av2 = 0.f;
#pragma unroll
    for (int l = 0; l < 8; ++l) { float v = st[l]; a += v*pv[l]; av2 += v*pd[l]; }
    float part[6] = {0,0,0,0,0,0};
#pragma unroll 2
    for (int i = 0; i < 8; ++i) {
      int d = i*64 + lane;
      float x = imapT[((size_t)b*150 + p)*512 + d];
      float t = tmap[b*512+d];
#pragma unroll
      for (int m = 0; m < 4; ++m) {
        float c1 = W[m][0]*t + W[m][1] + W[m][4] + (W[m][2] + W[m][3]*t)*a;
        float c0 = W[m][1]*t + W[m][5]*t*a;
        part[m] += elu_(c1*x + c0) * c3w[m*512+d];
      }
#pragma unroll
      for (int m = 0; m < 2; ++m) {
        float c1 = W[4+m][0]*t + W[4+m][1] + W[4+m][2]*a + W[4+m][3]*av2
                 + W[4+m][4]*a*av2 + W[4+m][5]*t*(a+av2);
        part[4+m] += elu_(c1*x + W[4+m][1]*t) * c4w[m*512+d];
      }
      // ans modules (mix3 row6, mix4 row7)
      float c16 = W[6][0]*t + W[6][1] + W[6][4] + (W[6][2] + W[6][3]*t)*a;
      float c06 = W[6][1]*t + W[6][5]*t*a;
      acc6[i] += elu_(c16*x + c06);
      float c17 = W[7][0]*t + W[7][1] + W[7][2]*a + W[7][3]*av2
                + W[7][4]*a*av2 + W[7][5]*t*(a+av2);
      acc7[i] += elu_(c17*x + W[7][1]*t);
    }
#pragma unroll
    for (int m = 0; m < 6; ++m) {
#pragma unroll
      for (int off = 32; off; off >>= 1) part[m] += __shfl_down(part[m], off);
    }
    if (lane == 0) {
      const float* w = wmod + b*9;
      float r3  = w[0]*(part[0]+c3b[0]) + w[1]*(part[1]+c3b[1])
                + w[2]*(part[2]+c3b[2]) + w[3]*(part[3]+c3b[3]);
      float r45 = w[4]*(part[4]+c4b[0]) + w[5]*(part[5]+c4b[1]);
      s3[b*150+p] = r3; s45[b*150+p] = r45;
    }
  }
#pragma unroll
  for (int i = 0; i < 8; ++i) {
    wpart[wave][0][i*64+lane] = acc6[i];
    wpart[wave][1][i*64+lane] = acc7[i];
  }
  __syncthreads();
  for (int e = threadIdx.x; e < 1024; e += 256) {
    int which = e >> 9, d = e & 511;
    float s = wpart[0][which][d] + wpart[1][which][d]
            + wpart[2][which][d] + wpart[3][which][d];
    part67[(((size_t)b*19 + pb)*2 + which)*512 + d] = s;
  }
}

// ---------------------------------------------------------------------------
// reduce part67 over the 19 p-blocks -> pooled6/7 (means)
// ---------------------------------------------------------------------------
__global__ __launch_bounds__(256)
void reduce67_k(const float* __restrict__ part67, float* __restrict__ pooled67)
{
  int b = blockIdx.x;
  for (int e = threadIdx.x; e < 1024; e += 256) {
    int which = e >> 9, d = e & 511;
    float s = 0.f;
    for (int pb = 0; pb < 19; ++pb)
      s += part67[(((size_t)b*19 + pb)*2 + which)*512 + d];
    pooled67[(size_t)which*32768 + b*512 + d] = s * (1.f/150.f);
  }
}

// ---------------------------------------------------------------------------
// blended stack/p/mem update (9-way blend collapsed algebraically)
// ---------------------------------------------------------------------------
__global__ __launch_bounds__(256)
void update_k(const float* __restrict__ wmod, float* __restrict__ pvec,
              float* __restrict__ stack,
              const float* __restrict__ s3, const float* __restrict__ s45,
              float* __restrict__ mem, const float* __restrict__ mem67)
{
  int b = blockIdx.x;
  __shared__ float wsh[9], pls[8], pds[8];
  if (threadIdx.x < 9) wsh[threadIdx.x] = wmod[b*9+threadIdx.x];
  if (threadIdx.x < 8) pls[threadIdx.x] = pvec[b*8+threadIdx.x];
  __syncthreads();
  if (threadIdx.x < 8) {
    int l = threadIdx.x;
    pds[l] = (l < 7 ? pls[l+1] : 0.f) + (l == 0 ? pls[0] : 0.f);
  }
  __syncthreads();
  float W03 = wsh[0]+wsh[1]+wsh[2]+wsh[3];
  float W45 = wsh[4]+wsh[5];
  float WP = W03 + wsh[6] + wsh[8];
  float WD = W45 + wsh[7];
  for (int e = threadIdx.x; e < 1200; e += 256) {
    int p = e >> 3, l = e & 7;
    size_t idx = ((size_t)b*150 + p)*8 + l;
    float pl = pls[l], pdl = pds[l];
    stack[idx] = stack[idx]*(1.f - W03*pl - W45*pdl)
               + pl*s3[b*150+p] + pdl*s45[b*150+p];
  }
  float w6v = wsh[6], w7v = wsh[7];
  for (int d = threadIdx.x; d < 512; d += 256) {
    mem[b*512+d] = w6v*mem67[b*512+d] + w7v*mem67[32768 + b*512+d]
                 + (1.f - w6v - w7v)*mem[b*512+d];
  }
  __syncthreads();
  if (threadIdx.x < 8) pvec[b*8+threadIdx.x] = WP*pls[threadIdx.x] + WD*pds[threadIdx.x];
}

// ---------------------------------------------------------------------------
__global__ __launch_bounds__(256)
void imp_k(const float* __restrict__ part, float* __restrict__ out)
{
  int lane = threadIdx.x & 63, wave = threadIdx.x >> 6;
  float acc = 0.f;
  for (int i = threadIdx.x; i < 576; i += 256) acc += part[i];
#pragma unroll
  for (int off = 32; off; off >>= 1) acc += __shfl_down(acc, off);
  __shared__ float red[4];
  if (lane == 0) red[wave] = acc;
  __syncthreads();
  if (threadIdx.x == 0) out[0] = red[0]+red[1]+red[2]+red[3];
}

// ---------------------------------------------------------------------------
extern "C" void kernel_launch(void* const* d_in, const int* in_sizes, int n_in,
                              void* d_out, int out_size, void* d_ws, size_t ws_size,
                              hipStream_t stream)
{
  (void)in_sizes; (void)n_in; (void)out_size; (void)ws_size;
  const float* image = (const float*)d_in[0];
  const int*   ques  = (const int*)d_in[1];
  const int*   qlen  = (const int*)d_in[2];
  const float* embedW= (const float*)d_in[3];
  const float* Wi_f  = (const float*)d_in[4];
  const float* Wh_f  = (const float*)d_in[5];
  const float* b_f   = (const float*)d_in[6];
  const float* Wi_b  = (const float*)d_in[7];
  const float* Wh_b  = (const float*)d_in[8];
  const float* b_b   = (const float*)d_in[9];
  const float* W1    = (const float*)d_in[10];
  const float* b1    = (const float*)d_in[11];
  const float* W2w   = (const float*)d_in[12];
  const float* W2b   = (const float*)d_in[13];
  const float* W3    = (const float*)d_in[14];
  const float* c0    = (const float*)d_in[15];
  const float* Wmod  = (const float*)d_in[16];
  const float* ic1w  = (const float*)d_in[17];
  const float* ic1b  = (const float*)d_in[18];
  const float* ic2w  = (const float*)d_in[19];
  const float* ic2b  = (const float*)d_in[20];
  const float* i2mw  = (const float*)d_in[21];
  const float* i2mb  = (const float*)d_in[22];
  const float* t2mw  = (const float*)d_in[23];
  const float* t2mb  = (const float*)d_in[24];
  const float* c3cw  = (const float*)d_in[26];
  const float* c3cb  = (const float*)d_in[27];
  const float* c4cw  = (const float*)d_in[29];
  const float* c4cb  = (const float*)d_in[30];
  const float* ansW  = (const float*)d_in[32];
  const float* ansb  = (const float*)d_in[33];
  const float* o1w   = (const float*)d_in[34];
  const float* o1b   = (const float*)d_in[35];
  const float* o2w   = (const float*)d_in[36];
  const float* o2b   = (const float*)d_in[37];
  const float* c3ow  = (const float*)d_in[25];
  const float* c4ow  = (const float*)d_in[28];
  const float* aow   = (const float*)d_in[31];
  float* out = (float*)d_out;
  float* ws  = (float*)d_ws;

  size_t off = 0;
  auto alloc = [&](size_t n){ float* p = ws + off; off += n; return p; };
  float* imgT  = alloc(64ull*150*640);   // also imapT after conv chain
  float* X1T   = alloc(64ull*150*512);   // conv2 runs in place on this
  float* imapT = imgT;
  float* wT1   = alloc(640*512);
  float* wT2   = alloc(512*512);
  float* wT3   = alloc(512*512);
  float* xWfb  = alloc(64ull*30*1024);
  float* xWbb  = alloc(64ull*30*1024);
  float* lout  = alloc(64ull*30*512);
  float* qbuf  = alloc(64*512);
  float* stck  = alloc(64*150*8);
  float* pvec  = alloc(64*8);
  float* memb  = alloc(64*512);
  float* cprev = alloc(64*512);
  float* tmp1a = alloc(9ull*64*512);
  float* ubuf  = alloc(64*512);
  float* wmw   = alloc(64*9);
  float* impp  = alloc(9*64);
  float* swb   = alloc(48);
  float* s3b   = alloc(64*150);
  float* s45b  = alloc(64*150);
  float* part67= alloc(64ull*19*2*512);
  float* pl67  = alloc(2*64*512);
  float* m67   = alloc(2*64*512);
  float* tmapb = alloc(64*512);
  float* h1b   = alloc(64*1024);
  unsigned* whp = (unsigned*)alloc(2*128*1024);

  init_k<<<320, 256, 0, stream>>>(c0, c3ow, c4ow, aow, stck, pvec, memb, cprev, swb);
  pack_k<<<1024, 256, 0, stream>>>(Wh_f, Wh_b, whp);
  transpose_k<<<dim3(5,20,64), 256, 0, stream>>>(image, imgT, 640, 150);
  transpose_k<<<dim3(20,16,1), 256, 0, stream>>>(ic1w, wT1, 512, 640);
  transpose_k<<<dim3(16,16,1), 256, 0, stream>>>(ic2w, wT2, 512, 512);
  transpose_k<<<dim3(16,16,1), 256, 0, stream>>>(i2mw, wT3, 512, 512);

  // embedding @ Wi (+bias), both directions (gather fused)
  rowgemm_k<16,2><<<dim3(2,120), 256, 0, stream>>>(
      embedW, ques, 300, Wi_f, b_f, xWfb, 1920, 1024, 0);
  rowgemm_k<16,2><<<dim3(2,120), 256, 0, stream>>>(
      embedW, ques, 300, Wi_b, b_b, xWbb, 1920, 1024, 0);

  // conv chain (row-GEMM over 9600 (b,pixel) rows); conv2 in place
  rowgemm_k<16,2><<<dim3(1,600), 256, 0, stream>>>(
      imgT, (const int*)nullptr, 640, wT1, ic1b, X1T, 9600, 512, 1);
  rowgemm_k<16,2><<<dim3(1,600), 256, 0, stream>>>(
      X1T, (const int*)nullptr, 512, wT2, ic2b, X1T, 9600, 512, 0);
  rowgemm_k<16,2><<<dim3(1,600), 256, 0, stream>>>(
      X1T, (const int*)nullptr, 512, wT3, i2mb, imapT, 9600, 512, 0);

  lstm_k<<<64, 1024, 0, stream>>>(xWfb, xWbb, whp, qlen, lout, qbuf);

  // hoisted: tmp1all[t] = q @ W1[t] + b1, all 9 t in one launch
  gemm64_k<<<dim3(8,8,9), 512, 0, stream>>>(
      qbuf, 0, 9, (const float*)nullptr, 0,
      W1, 262144, b1, 0, tmp1a, 32768, 512, 0);

  for (int t = 0; t < 9; ++t) {
    // u = [tmp1_t, c_prev] @ W2 + b
    gemm64_k<<<dim3(8,8,1), 512, 0, stream>>>(
        tmp1a + (size_t)t*32768, 0, 9, cprev, 512,
        W2w, 0, W2b, 0, ubuf, 0, 512, 0);
    kc_k<<<64, 256, 0, stream>>>(ubuf, Wmod, wmw, impp, t);
    attn_k<<<64, 256, 0, stream>>>(lout, ubuf, W3, cprev);
    // tmap = c @ t2m + b
    gemm64_k<<<dim3(8,8,1), 512, 0, stream>>>(
        cprev, 0, 9, (const float*)nullptr, 0,
        t2mw, 0, t2mb, 0, tmapb, 0, 512, 0);
    modpool_k<<<dim3(19,64), 256, 0, stream>>>(
        imapT, tmapb, stck, pvec, swb, c3cw, c3cb, c4cw, c4cb, wmw,
        s3b, s45b, part67);
    reduce67_k<<<64, 256, 0, stream>>>(part67, pl67);
    // mem6/mem7 = [pooled, tmap] @ ansW[z] + ansb[z]   (z = 0,1)
    gemm64_k<<<dim3(8,8,2), 512, 0, stream>>>(
        pl67, 32768, 9, tmapb, 512,
        ansW, 524288, ansb, 512, m67, 32768, 512, 0);
    update_k<<<64, 256, 0, stream>>>(wmw, pvec, stck, s3b, s45b, memb, m67);
  }

  // h1 = elu([q, mem] @ out1 + b);  logits = h1 @ out2 + b
  gemm64_k<<<dim3(16,8,1), 512, 0, stream>>>(
      qbuf, 0, 9, memb, 512, o1w, 0, o1b, 0, h1b, 0, 1024, 1);
  gemm64_k<<<dim3(1,8,1), 512, 0, stream>>>(
      h1b, 0, 10, (const float*)nullptr, 0, o2w, 0, o2b, 0, out, 0, 32, 0);
  imp_k<<<1, 256, 0, stream>>>(impp, out + 2048);
}

// Round 3
// 1698.935 us; speedup vs baseline: 3.2187x; 1.9781x over previous
//
#include <hip/hip_runtime.h>
#include <math.h>

#define DEV __device__ __forceinline__

DEV float fexp(float x){ return __expf(x); }
DEV float elu_(float x){ return x > 0.f ? x : fexp(x) - 1.f; }
DEV float sigm_(float x){ return 1.f/(1.f + fexp(-x)); }
DEV float tanh_(float x){ float e = fexp(2.f*x); return 1.f - 2.f/(e + 1.f); }
DEV unsigned bf16r(float x){ unsigned u = __float_as_uint(x);
  return (u + 0x7fffu + ((u>>16)&1u)) >> 16; }
DEV float blo(unsigned u){ return __uint_as_float(u << 16); }
DEV float bhi(unsigned u){ return __uint_as_float(u & 0xffff0000u); }

// ---------------------------------------------------------------------------
// init: stack=0, p=[1,0..], mem=0, c_prev=tile(c_0), pl67=0, softmax op-weights
// ---------------------------------------------------------------------------
__global__ __launch_bounds__(256)
void init_k(const float* __restrict__ c0, const float* __restrict__ c3ow,
            const float* __restrict__ c4ow, const float* __restrict__ aow,
            float* __restrict__ stack, float* __restrict__ pvec,
            float* __restrict__ mem, float* __restrict__ cprev,
            float* __restrict__ swb, float* __restrict__ pl67)
{
  int idx = blockIdx.x*256 + threadIdx.x;
  int stride = gridDim.x*256;
  for (int i = idx; i < 64*150*8; i += stride) stack[i] = 0.f;
  for (int i = idx; i < 64*8;    i += stride) pvec[i] = ((i & 7) == 0) ? 1.f : 0.f;
  for (int i = idx; i < 64*512;  i += stride) mem[i] = 0.f;
  for (int i = idx; i < 64*512;  i += stride) cprev[i] = c0[i & 511];
  for (int i = idx; i < 2*64*512; i += stride) pl67[i] = 0.f;
  if (idx < 8) {
    const float* ow = (idx < 4) ? (c3ow + idx*6)
                    : (idx < 6) ? (c4ow + (idx-4)*6)
                                : (aow  + (idx-6)*6);
    float mx = ow[0];
    for (int m = 1; m < 6; ++m) mx = fmaxf(mx, ow[m]);
    float e[6]; float s = 0.f;
    for (int m = 0; m < 6; ++m) { e[m] = fexp(ow[m]-mx); s += e[m]; }
    for (int m = 0; m < 6; ++m) swb[idx*6+m] = e[m]/s;
  }
}

// ---------------------------------------------------------------------------
// pack Wh (both dirs) into uint4 of 4 bf16-pairs:
// whp4[(dir*32+kg)*1024 + n].{x..w} = pair(k = kg*8 + 2j, 2j+1) at col n
// ---------------------------------------------------------------------------
__global__ __launch_bounds__(256)
void pack4_k(const float* __restrict__ Whf, const float* __restrict__ Whb,
             uint4* __restrict__ whp4)
{
  int idx = blockIdx.x*256 + threadIdx.x;   // 2*32*1024
  int dir = idx >> 15;
  int rem = idx & 32767;
  int kg  = rem >> 10;
  int n   = rem & 1023;
  const float* Wh = dir ? Whb : Whf;
  unsigned v[4];
#pragma unroll
  for (int j = 0; j < 4; ++j) {
    int k = kg*8 + 2*j;
    float lo = Wh[(size_t)k*1024 + n];
    float hi = Wh[(size_t)(k+1)*1024 + n];
    v[j] = bf16r(lo) | (bf16r(hi) << 16);
  }
  whp4[idx] = make_uint4(v[0], v[1], v[2], v[3]);
}

// ---------------------------------------------------------------------------
// batched tiled transpose: src[b][r][c] -> dst[b][c][r]
// ---------------------------------------------------------------------------
__global__ __launch_bounds__(256)
void transpose_k(const float* __restrict__ src, float* __restrict__ dst,
                 int rows, int cols)
{
  __shared__ float tile[32][33];
  const size_t base = (size_t)blockIdx.z * rows * cols;
  int c0 = blockIdx.x*32, r0 = blockIdx.y*32;
  int tx = threadIdx.x & 31, ty = threadIdx.x >> 5;
  for (int i = 0; i < 32; i += 8) {
    int r = r0+ty+i, c = c0+tx;
    if (r < rows && c < cols) tile[ty+i][tx] = src[base + (size_t)r*cols + c];
  }
  __syncthreads();
  for (int i = 0; i < 32; i += 8) {
    int c = c0+ty+i, r = r0+tx;
    if (c < cols && r < rows) dst[base + (size_t)c*rows + r] = tile[tx][ty+i];
  }
}

// ---------------------------------------------------------------------------
// generic row-GEMM (embed + convs): C[r][n] = act(A@B + bias)
// ---------------------------------------------------------------------------
template<int RT, int CPT>
__global__ __launch_bounds__(256)
void rowgemm_k(const float* __restrict__ A, const int* __restrict__ gather, int K1,
               const float* __restrict__ B, const float* __restrict__ bias,
               float* __restrict__ C, int R, int N, int act)
{
  const int tx = threadIdx.x;
  const int n0 = blockIdx.x * (256*CPT);
  const int r0 = blockIdx.y * RT;
  __shared__ __align__(16) float Ast[32][RT];
  float acc[RT][CPT];
#pragma unroll
  for (int r = 0; r < RT; ++r)
#pragma unroll
    for (int c = 0; c < CPT; ++c) acc[r][c] = 0.f;

  int nn[CPT]; bool nv[CPT];
#pragma unroll
  for (int c = 0; c < CPT; ++c) { nn[c] = n0 + tx + c*256; nv[c] = nn[c] < N; }

  for (int kb = 0; kb < K1; kb += 32) {
    const int klim = (K1 - kb < 32) ? (K1 - kb) : 32;
    __syncthreads();
    for (int e = tx; e < RT*32; e += 256) {
      int r = e >> 5, kk = e & 31;
      float v = 0.f;
      int rr = r0 + r;
      if (rr < R && kk < klim) {
        int arow = gather ? gather[rr] : rr;
        v = A[(size_t)arow*K1 + kb + kk];
      }
      Ast[kk][r] = v;
    }
    __syncthreads();
    const float* Brow = B + (size_t)kb*N;
    auto body = [&](int kk) {
      float av[RT];
#pragma unroll
      for (int r4 = 0; r4 < RT; r4 += 4) {
        float4 t4 = *(const float4*)&Ast[kk][r4];
        av[r4] = t4.x; av[r4+1] = t4.y; av[r4+2] = t4.z; av[r4+3] = t4.w;
      }
      float w[CPT];
#pragma unroll
      for (int c = 0; c < CPT; ++c) w[c] = nv[c] ? Brow[(size_t)kk*N + nn[c]] : 0.f;
#pragma unroll
      for (int r = 0; r < RT; ++r)
#pragma unroll
        for (int c = 0; c < CPT; ++c) acc[r][c] += av[r]*w[c];
    };
    if (klim == 32) {
#pragma unroll 8
      for (int kk = 0; kk < 32; ++kk) body(kk);
    } else {
      for (int kk = 0; kk < klim; ++kk) body(kk);
    }
  }
#pragma unroll
  for (int r = 0; r < RT; ++r) {
    int rr = r0 + r; if (rr >= R) continue;
#pragma unroll
    for (int c = 0; c < CPT; ++c) {
      if (!nv[c]) continue;
      float v = acc[r][c] + (bias ? bias[nn[c]] : 0.f);
      if (act == 1) v = elu_(v);
      C[(size_t)rr*N + nn[c]] = v;
    }
  }
}

// ---------------------------------------------------------------------------
// 64-row batch GEMM, K-split across waves (latency-optimized):
// C[z][r][n] = act( [A1|A2][r][K1+K2] @ B[z] + bias[z] )
// block: 512 thr = 8 waves; wave = K-segment; lane = 1 of 64 cols; 8 rows.
// B-tile read exactly once per block. K1 in {512,1024} (pow2), K2 in {0,512}.
// ---------------------------------------------------------------------------
__global__ __launch_bounds__(512)
void gemm64b_k(const float* __restrict__ A1, long zA1, int K1log,
               const float* __restrict__ A2, int K2,
               const float* __restrict__ B, long zB,
               const float* __restrict__ bias, int zbias,
               float* __restrict__ C, long zC, int N, int act)
{
  const int K1 = 1 << K1log;
  const int Kt = K1 + K2;
  __shared__ __align__(16) float As[8][1024];
  __shared__ float part[8][8][64];
  const int tid = threadIdx.x;
  const int z = blockIdx.z;
  const int r0 = blockIdx.y*8;

  {
    const float* a1 = A1 + (size_t)z*zA1;
    const int nf4 = (8*K1) >> 2;
    for (int e4 = tid; e4 < nf4; e4 += 512) {
      int r = e4 >> (K1log-2);
      int k4 = (e4 & ((K1>>2)-1)) << 2;
      *(float4*)&As[r][k4] = *(const float4*)&a1[(size_t)(r0+r)*K1 + k4];
    }
    if (K2 > 0) {  // K2 == 512
      for (int e4 = tid; e4 < 1024; e4 += 512) {
        int r = e4 >> 7;
        int k4 = (e4 & 127) << 2;
        *(float4*)&As[r][K1+k4] = *(const float4*)&A2[(size_t)(r0+r)*512 + k4];
      }
    }
  }
  __syncthreads();

  const int lane = tid & 63, w = tid >> 6;
  const int n = blockIdx.x*64 + lane;
  const bool nv = n < N;
  const int kseg = Kt >> 3;
  const int k0 = w*kseg;
  const float* Bp = B + (size_t)z*zB + (size_t)k0*N + (nv ? n : 0);
  float acc[8] = {0,0,0,0,0,0,0,0};
#pragma unroll 8
  for (int kk = 0; kk < kseg; ++kk) {
    float bv = nv ? Bp[(size_t)kk*N] : 0.f;
    int k = k0 + kk;
#pragma unroll
    for (int r = 0; r < 8; ++r) acc[r] += As[r][k]*bv;
  }
#pragma unroll
  for (int r = 0; r < 8; ++r) part[w][r][lane] = acc[r];
  __syncthreads();
  {
    int r = tid >> 6, c = tid & 63;
    int nn = blockIdx.x*64 + c;
    if (nn < N) {
      float s = 0.f;
#pragma unroll
      for (int w2 = 0; w2 < 8; ++w2) s += part[w2][r][c];
      s += bias ? bias[(size_t)z*zbias + nn] : 0.f;
      if (act == 1) s = elu_(s);
      C[(size_t)z*zC + (size_t)(r0+r)*N + nn] = s;
    }
  }
}

// ---------------------------------------------------------------------------
// bidirectional masked LSTM; 128 blocks = (dir, batch); Wh as uint4 bf16-pairs
// ---------------------------------------------------------------------------
__global__ __launch_bounds__(1024)
void lstm4_k(const float* __restrict__ xWf, const float* __restrict__ xWb,
             const uint4* __restrict__ whp4,
             const int* __restrict__ qlen, float* __restrict__ lstm_out,
             float* __restrict__ qout)
{
  int dir = blockIdx.x >> 6;
  int b   = blockIdx.x & 63;
  const float* xW = dir ? xWb : xWf;
  const uint4* Wp = whp4 + (size_t)dir*32768 + threadIdx.x;
  __shared__ __align__(16) float hl[256];
  __shared__ __align__(16) float cl[256];
  __shared__ float zl[1024];
  int tid = threadIdx.x;
  if (tid < 256) { hl[tid] = 0.f; cl[tid] = 0.f; }
  int len = qlen[b];
  for (int ss = 0; ss < 30; ++ss) {
    int s = dir ? (29-ss) : ss;
    __syncthreads();           // h/c ready
    float z = xW[((size_t)b*30 + s)*1024 + tid];
#pragma unroll 4
    for (int kg = 0; kg < 32; ++kg) {
      uint4 w = Wp[(size_t)kg*1024];
      float4 ha = *(const float4*)&hl[kg*8];
      float4 hb = *(const float4*)&hl[kg*8+4];
      z += ha.x*blo(w.x) + ha.y*bhi(w.x) + ha.z*blo(w.y) + ha.w*bhi(w.y)
         + hb.x*blo(w.z) + hb.y*bhi(w.z) + hb.z*blo(w.w) + hb.w*bhi(w.w);
    }
    zl[tid] = z;
    __syncthreads();
    if (tid < 256) {
      float iv = zl[tid], fv = zl[256+tid], gv = zl[512+tid], ov = zl[768+tid];
      float cn = sigm_(fv)*cl[tid] + sigm_(iv)*tanh_(gv);
      float hn = sigm_(ov)*tanh_(cn);
      bool m = s < len;
      lstm_out[((size_t)b*30 + s)*512 + dir*256 + tid] = m ? hn : 0.f;
      if (m) { hl[tid] = hn; cl[tid] = cn; }
    }
  }
  __syncthreads();
  if (tid < 256) qout[(size_t)b*512 + dir*256 + tid] = hl[tid];
}

// ---------------------------------------------------------------------------
// fused kc + attn: w[9]+entropy from u; attention context -> cprev
// ---------------------------------------------------------------------------
__global__ __launch_bounds__(256)
void kcattn_k(const float* __restrict__ u, const float* __restrict__ Wmod,
              const float* __restrict__ lstm_out, const float* __restrict__ W3,
              float* __restrict__ wout, float* __restrict__ imp_part,
              float* __restrict__ cout, int t)
{
  int b = blockIdx.x;
  int lane = threadIdx.x & 63, wave = threadIdx.x >> 6;
  __shared__ float ush[512];
  __shared__ float wl[9];
  __shared__ float sc[32], at[32];
  ush[threadIdx.x]     = u[b*512 + threadIdx.x];
  ush[256+threadIdx.x] = u[b*512 + 256 + threadIdx.x];
  __syncthreads();
  for (int m = wave; m < 9; m += 4) {
    float acc = 0.f;
    for (int k = lane; k < 512; k += 64) acc += ush[k]*Wmod[k*9+m];
#pragma unroll
    for (int off = 32; off; off >>= 1) acc += __shfl_down(acc, off);
    if (lane == 0) wl[m] = acc;
  }
  for (int s = wave; s < 30; s += 4) {
    float acc = 0.f;
    const float* lo = lstm_out + ((size_t)b*30 + s)*512;
    for (int h = lane; h < 512; h += 64) acc += lo[h]*ush[h]*W3[h];
#pragma unroll
    for (int off = 32; off; off >>= 1) acc += __shfl_down(acc, off);
    if (lane == 0) sc[s] = acc;
  }
  __syncthreads();
  if (threadIdx.x == 0) {
    float mx = wl[0];
    for (int m = 1; m < 9; ++m) mx = fmaxf(mx, wl[m]);
    float s = 0.f;
    for (int m = 0; m < 9; ++m) s += fexp(wl[m]-mx);
    float ls = logf(s);
    float ent = 0.f;
    for (int m = 0; m < 9; ++m) {
      float l = wl[m]-mx-ls;
      float w = fexp(l);
      wout[b*9+m] = w;
      ent -= w*l;
    }
    imp_part[t*64+b] = ent;
  }
  if (wave == 1) {
    float v = (lane < 30) ? sc[lane] : -3.4e38f;
    float mx = v;
#pragma unroll
    for (int off = 32; off; off >>= 1) mx = fmaxf(mx, __shfl_xor(mx, off));
    float e = (lane < 30) ? fexp(v-mx) : 0.f;
    float ssum = e;
#pragma unroll
    for (int off = 32; off; off >>= 1) ssum += __shfl_xor(ssum, off);
    if (lane < 30) at[lane] = e/ssum;
  }
  __syncthreads();
  for (int h = threadIdx.x; h < 512; h += 256) {
    float acc = 0.f;
#pragma unroll 6
    for (int s = 0; s < 30; ++s) acc += at[s]*lstm_out[((size_t)b*30 + s)*512 + h];
    cout[b*512+h] = acc;
  }
}

// ---------------------------------------------------------------------------
// fused modules + pooled partials + stack update.
// grid (x=b 64, y=pb 19): same-b blocks are 64 apart -> same XCD (L2 reuse).
// pooled partials accumulated into pl67 via atomicAdd (scaled 1/150).
// ---------------------------------------------------------------------------
__global__ __launch_bounds__(256)
void modules_k(const float* __restrict__ imapT, const float* __restrict__ tmap,
               float* __restrict__ stack, const float* __restrict__ pvec,
               const float* __restrict__ swb, const float* __restrict__ c3w,
               const float* __restrict__ c3b, const float* __restrict__ c4w,
               const float* __restrict__ c4b, const float* __restrict__ wmod,
               float* __restrict__ pl67)
{
  int b  = blockIdx.x;
  int pb = blockIdx.y;
  int lane = threadIdx.x & 63, wave = threadIdx.x >> 6;
  __shared__ float pv[8], pd[8], wm[9];
  __shared__ float wpart[4][2][512];
  if (threadIdx.x < 8) pv[threadIdx.x] = pvec[b*8+threadIdx.x];
  if (threadIdx.x >= 64 && threadIdx.x < 73) wm[threadIdx.x-64] = wmod[b*9 + threadIdx.x-64];
  __syncthreads();
  if (threadIdx.x < 8) {
    int l = threadIdx.x;
    pd[l] = (l < 7 ? pv[l+1] : 0.f) + (l == 0 ? pv[0] : 0.f);
  }
  __syncthreads();

  float W[8][6];
#pragma unroll
  for (int m = 0; m < 8; ++m)
#pragma unroll
    for (int i = 0; i < 6; ++i) W[m][i] = swb[m*6+i];
  float W03 = wm[0]+wm[1]+wm[2]+wm[3];
  float W45 = wm[4]+wm[5];

  float acc6[8], acc7[8];
#pragma unroll
  for (int i = 0; i < 8; ++i) { acc6[i] = 0.f; acc7[i] = 0.f; }

  for (int pi = 0; pi < 2; ++pi) {
    int p = pb*8 + wave*2 + pi;
    if (p >= 150) continue;
    const float* st = stack + ((size_t)b*150 + p)*8;
    float a = 0.f, av2 = 0.f;
#pragma unroll
    for (int l = 0; l < 8; ++l) { float v = st[l]; a += v*pv[l]; av2 += v*pd[l]; }
    float part[6] = {0,0,0,0,0,0};
#pragma unroll 2
    for (int i = 0; i < 8; ++i) {
      int d = i*64 + lane;
      float x = imapT[((size_t)b*150 + p)*512 + d];
      float t = tmap[b*512+d];
#pragma unroll
      for (int m = 0; m < 4; ++m) {
        float c1 = W[m][0]*t + W[m][1] + W[m][4] + (W[m][2] + W[m][3]*t)*a;
        float c0 = W[m][1]*t + W[m][5]*t*a;
        part[m] += elu_(c1*x + c0) * c3w[m*512+d];
      }
#pragma unroll
      for (int m = 0; m < 2; ++m) {
        float c1 = W[4+m][0]*t + W[4+m][1] + W[4+m][2]*a + W[4+m][3]*av2
                 + W[4+m][4]*a*av2 + W[4+m][5]*t*(a+av2);
        part[4+m] += elu_(c1*x + W[4+m][1]*t) * c4w[m*512+d];
      }
      float c16 = W[6][0]*t + W[6][1] + W[6][4] + (W[6][2] + W[6][3]*t)*a;
      float c06 = W[6][1]*t + W[6][5]*t*a;
      acc6[i] += elu_(c16*x + c06);
      float c17 = W[7][0]*t + W[7][1] + W[7][2]*a + W[7][3]*av2
                + W[7][4]*a*av2 + W[7][5]*t*(a+av2);
      acc7[i] += elu_(c17*x + W[7][1]*t);
    }
#pragma unroll
    for (int m = 0; m < 6; ++m) {
#pragma unroll
      for (int off = 32; off; off >>= 1) part[m] += __shfl_down(part[m], off);
      part[m] = __shfl(part[m], 0);
    }
    float r3  = wm[0]*(part[0]+c3b[0]) + wm[1]*(part[1]+c3b[1])
              + wm[2]*(part[2]+c3b[2]) + wm[3]*(part[3]+c3b[3]);
    float r45 = wm[4]*(part[4]+c4b[0]) + wm[5]*(part[5]+c4b[1]);
    if (lane < 8) {
      int l = lane;
      size_t idx = ((size_t)b*150 + p)*8 + l;
      stack[idx] = stack[idx]*(1.f - W03*pv[l] - W45*pd[l])
                 + pv[l]*r3 + pd[l]*r45;
    }
  }
#pragma unroll
  for (int i = 0; i < 8; ++i) {
    wpart[wave][0][i*64+lane] = acc6[i];
    wpart[wave][1][i*64+lane] = acc7[i];
  }
  __syncthreads();
  for (int e = threadIdx.x; e < 1024; e += 256) {
    int which = e >> 9, d = e & 511;
    float s = wpart[0][which][d] + wpart[1][which][d]
            + wpart[2][which][d] + wpart[3][which][d];
    atomicAdd(&pl67[(size_t)which*32768 + b*512 + d], s * (1.f/150.f));
  }
}

// ---------------------------------------------------------------------------
// mem blend + pvec update + zero pl67 for next t
// ---------------------------------------------------------------------------
__global__ __launch_bounds__(256)
void update2_k(const float* __restrict__ wmod, float* __restrict__ pvec,
               float* __restrict__ mem, const float* __restrict__ m67,
               float* __restrict__ pl67)
{
  int b = blockIdx.x;
  __shared__ float wsh[9], pls[8], pds[8];
  if (threadIdx.x < 9) wsh[threadIdx.x] = wmod[b*9+threadIdx.x];
  if (threadIdx.x < 8) pls[threadIdx.x] = pvec[b*8+threadIdx.x];
  __syncthreads();
  if (threadIdx.x < 8) {
    int l = threadIdx.x;
    pds[l] = (l < 7 ? pls[l+1] : 0.f) + (l == 0 ? pls[0] : 0.f);
  }
  __syncthreads();
  float WP = wsh[0]+wsh[1]+wsh[2]+wsh[3] + wsh[6] + wsh[8];
  float WD = wsh[4]+wsh[5] + wsh[7];
  float w6v = wsh[6], w7v = wsh[7];
  for (int d = threadIdx.x; d < 512; d += 256) {
    mem[b*512+d] = w6v*m67[b*512+d] + w7v*m67[32768 + b*512+d]
                 + (1.f - w6v - w7v)*mem[b*512+d];
  }
  for (int e = threadIdx.x; e < 1024; e += 256) {
    int which = e >> 9, d = e & 511;
    pl67[(size_t)which*32768 + b*512 + d] = 0.f;
  }
  __syncthreads();
  if (threadIdx.x < 8) pvec[b*8+threadIdx.x] = WP*pls[threadIdx.x] + WD*pds[threadIdx.x];
}

// ---------------------------------------------------------------------------
__global__ __launch_bounds__(256)
void imp_k(const float* __restrict__ part, float* __restrict__ out)
{
  int lane = threadIdx.x & 63, wave = threadIdx.x >> 6;
  float acc = 0.f;
  for (int i = threadIdx.x; i < 576; i += 256) acc += part[i];
#pragma unroll
  for (int off = 32; off; off >>= 1) acc += __shfl_down(acc, off);
  __shared__ float red[4];
  if (lane == 0) red[wave] = acc;
  __syncthreads();
  if (threadIdx.x == 0) out[0] = red[0]+red[1]+red[2]+red[3];
}

// ---------------------------------------------------------------------------
extern "C" void kernel_launch(void* const* d_in, const int* in_sizes, int n_in,
                              void* d_out, int out_size, void* d_ws, size_t ws_size,
                              hipStream_t stream)
{
  (void)in_sizes; (void)n_in; (void)out_size; (void)ws_size;
  const float* image = (const float*)d_in[0];
  const int*   ques  = (const int*)d_in[1];
  const int*   qlen  = (const int*)d_in[2];
  const float* embedW= (const float*)d_in[3];
  const float* Wi_f  = (const float*)d_in[4];
  const float* Wh_f  = (const float*)d_in[5];
  const float* b_f   = (const float*)d_in[6];
  const float* Wi_b  = (const float*)d_in[7];
  const float* Wh_b  = (const float*)d_in[8];
  const float* b_b   = (const float*)d_in[9];
  const float* W1    = (const float*)d_in[10];
  const float* b1    = (const float*)d_in[11];
  const float* W2w   = (const float*)d_in[12];
  const float* W2b   = (const float*)d_in[13];
  const float* W3    = (const float*)d_in[14];
  const float* c0    = (const float*)d_in[15];
  const float* Wmod  = (const float*)d_in[16];
  const float* ic1w  = (const float*)d_in[17];
  const float* ic1b  = (const float*)d_in[18];
  const float* ic2w  = (const float*)d_in[19];
  const float* ic2b  = (const float*)d_in[20];
  const float* i2mw  = (const float*)d_in[21];
  const float* i2mb  = (const float*)d_in[22];
  const float* t2mw  = (const float*)d_in[23];
  const float* t2mb  = (const float*)d_in[24];
  const float* c3ow  = (const float*)d_in[25];
  const float* c3cw  = (const float*)d_in[26];
  const float* c3cb  = (const float*)d_in[27];
  const float* c4ow  = (const float*)d_in[28];
  const float* c4cw  = (const float*)d_in[29];
  const float* c4cb  = (const float*)d_in[30];
  const float* aow   = (const float*)d_in[31];
  const float* ansW  = (const float*)d_in[32];
  const float* ansb  = (const float*)d_in[33];
  const float* o1w   = (const float*)d_in[34];
  const float* o1b   = (const float*)d_in[35];
  const float* o2w   = (const float*)d_in[36];
  const float* o2b   = (const float*)d_in[37];
  float* out = (float*)d_out;
  float* ws  = (float*)d_ws;

  size_t off = 0;
  auto alloc = [&](size_t n){ float* p = ws + off; off += n; return p; };
  float* imgT  = alloc(64ull*150*640);   // also imapT after conv chain
  float* X1T   = alloc(64ull*150*512);   // conv2 in place
  float* imapT = imgT;
  float* wT1   = alloc(640*512);
  float* wT2   = alloc(512*512);
  float* wT3   = alloc(512*512);
  float* xWfb  = alloc(64ull*30*1024);
  float* xWbb  = alloc(64ull*30*1024);
  float* lout  = alloc(64ull*30*512);
  float* qbuf  = alloc(64*512);
  float* stck  = alloc(64*150*8);
  float* pvec  = alloc(64*8);
  float* memb  = alloc(64*512);
  float* cprev = alloc(64*512);
  float* tmp1a = alloc(9ull*64*512);
  float* ubuf  = alloc(64*512);
  float* wmw   = alloc(64*9);
  float* impp  = alloc(9*64);
  float* swb   = alloc(48);
  float* pl67  = alloc(2*64*512);
  float* m67   = alloc(2*64*512);
  float* tmapb = alloc(64*512);
  float* h1b   = alloc(64*1024);
  uint4* whp4  = (uint4*)alloc(2*32*1024*4);

  init_k<<<320, 256, 0, stream>>>(c0, c3ow, c4ow, aow, stck, pvec, memb, cprev,
                                  swb, pl67);
  pack4_k<<<256, 256, 0, stream>>>(Wh_f, Wh_b, whp4);
  transpose_k<<<dim3(5,20,64), 256, 0, stream>>>(image, imgT, 640, 150);
  transpose_k<<<dim3(20,16,1), 256, 0, stream>>>(ic1w, wT1, 512, 640);
  transpose_k<<<dim3(16,16,1), 256, 0, stream>>>(ic2w, wT2, 512, 512);
  transpose_k<<<dim3(16,16,1), 256, 0, stream>>>(i2mw, wT3, 512, 512);

  // embedding @ Wi (+bias), both directions (gather fused)
  rowgemm_k<16,2><<<dim3(2,120), 256, 0, stream>>>(
      embedW, ques, 300, Wi_f, b_f, xWfb, 1920, 1024, 0);
  rowgemm_k<16,2><<<dim3(2,120), 256, 0, stream>>>(
      embedW, ques, 300, Wi_b, b_b, xWbb, 1920, 1024, 0);

  // conv chain (row-GEMM over 9600 (b,pixel) rows); conv2 in place
  rowgemm_k<16,2><<<dim3(1,600), 256, 0, stream>>>(
      imgT, (const int*)nullptr, 640, wT1, ic1b, X1T, 9600, 512, 1);
  rowgemm_k<16,2><<<dim3(1,600), 256, 0, stream>>>(
      X1T, (const int*)nullptr, 512, wT2, ic2b, X1T, 9600, 512, 0);
  rowgemm_k<16,2><<<dim3(1,600), 256, 0, stream>>>(
      X1T, (const int*)nullptr, 512, wT3, i2mb, imapT, 9600, 512, 0);

  lstm4_k<<<128, 1024, 0, stream>>>(xWfb, xWbb, whp4, qlen, lout, qbuf);

  // hoisted: tmp1all[t] = q @ W1[t] + b1, all 9 t in one launch
  gemm64b_k<<<dim3(8,8,9), 512, 0, stream>>>(
      qbuf, 0, 9, (const float*)nullptr, 0,
      W1, 262144, b1, 0, tmp1a, 32768, 512, 0);

  for (int t = 0; t < 9; ++t) {
    gemm64b_k<<<dim3(8,8,1), 512, 0, stream>>>(
        tmp1a + (size_t)t*32768, 0, 9, cprev, 512,
        W2w, 0, W2b, 0, ubuf, 0, 512, 0);
    kcattn_k<<<64, 256, 0, stream>>>(ubuf, Wmod, lout, W3, wmw, impp, cprev, t);
    gemm64b_k<<<dim3(8,8,1), 512, 0, stream>>>(
        cprev, 0, 9, (const float*)nullptr, 0,
        t2mw, 0, t2mb, 0, tmapb, 0, 512, 0);
    modules_k<<<dim3(64,19), 256, 0, stream>>>(
        imapT, tmapb, stck, pvec, swb, c3cw, c3cb, c4cw, c4cb, wmw, pl67);
    gemm64b_k<<<dim3(8,8,2), 512, 0, stream>>>(
        pl67, 32768, 9, tmapb, 512,
        ansW, 524288, ansb, 512, m67, 32768, 512, 0);
    update2_k<<<64, 256, 0, stream>>>(wmw, pvec, memb, m67, pl67);
  }

  // h1 = elu([q, mem] @ out1 + b);  logits = h1 @ out2 + b
  gemm64b_k<<<dim3(16,8,1), 512, 0, stream>>>(
      qbuf, 0, 9, memb, 512, o1w, 0, o1b, 0, h1b, 0, 1024, 1);
  gemm64b_k<<<dim3(1,8,1), 512, 0, stream>>>(
      h1b, 0, 10, (const float*)nullptr, 0, o2w, 0, o2b, 0, out, 0, 32, 0);
  imp_k<<<1, 256, 0, stream>>>(impp, out + 2048);
}

// Round 4
// 1183.977 us; speedup vs baseline: 4.6186x; 1.4349x over previous
//
#include <hip/hip_runtime.h>
#include <math.h>

#define DEV __device__ __forceinline__

DEV float fexp(float x){ return __expf(x); }
DEV float elu_(float x){ return x > 0.f ? x : fexp(x) - 1.f; }
DEV float sigm_(float x){ return 1.f/(1.f + fexp(-x)); }
DEV float tanh_(float x){ float e = fexp(2.f*x); return 1.f - 2.f/(e + 1.f); }
DEV unsigned bf16r(float x){ unsigned u = __float_as_uint(x);
  return (u + 0x7fffu + ((u>>16)&1u)) >> 16; }
DEV float blo(unsigned u){ return __uint_as_float(u << 16); }
DEV float bhi(unsigned u){ return __uint_as_float(u & 0xffff0000u); }

using frag  = __attribute__((ext_vector_type(8))) short;   // 8 bf16 (4 VGPRs)
using f32x4 = __attribute__((ext_vector_type(4))) float;   // MFMA acc

// ---------------------------------------------------------------------------
// init: stack=0, p=[1,0..], mem=0, c_prev=tile(c_0), pl67=0, softmax op-weights
// ---------------------------------------------------------------------------
__global__ __launch_bounds__(256)
void init_k(const float* __restrict__ c0, const float* __restrict__ c3ow,
            const float* __restrict__ c4ow, const float* __restrict__ aow,
            float* __restrict__ stack, float* __restrict__ pvec,
            float* __restrict__ mem, float* __restrict__ cprev,
            float* __restrict__ swb, float* __restrict__ pl67)
{
  int idx = blockIdx.x*256 + threadIdx.x;
  int stride = gridDim.x*256;
  for (int i = idx; i < 64*150*8; i += stride) stack[i] = 0.f;
  for (int i = idx; i < 64*8;    i += stride) pvec[i] = ((i & 7) == 0) ? 1.f : 0.f;
  for (int i = idx; i < 64*512;  i += stride) mem[i] = 0.f;
  for (int i = idx; i < 64*512;  i += stride) cprev[i] = c0[i & 511];
  for (int i = idx; i < 2*64*512; i += stride) pl67[i] = 0.f;
  if (idx < 8) {
    const float* ow = (idx < 4) ? (c3ow + idx*6)
                    : (idx < 6) ? (c4ow + (idx-4)*6)
                                : (aow  + (idx-6)*6);
    float mx = ow[0];
    for (int m = 1; m < 6; ++m) mx = fmaxf(mx, ow[m]);
    float e[6]; float s = 0.f;
    for (int m = 0; m < 6; ++m) { e[m] = fexp(ow[m]-mx); s += e[m]; }
    for (int m = 0; m < 6; ++m) swb[idx*6+m] = e[m]/s;
  }
}

// ---------------------------------------------------------------------------
// pack Wh (both dirs) into uint4 of 4 bf16-pairs (LSTM recurrent weights)
// ---------------------------------------------------------------------------
__global__ __launch_bounds__(256)
void pack4_k(const float* __restrict__ Whf, const float* __restrict__ Whb,
             uint4* __restrict__ whp4)
{
  int idx = blockIdx.x*256 + threadIdx.x;   // 2*32*1024
  int dir = idx >> 15;
  int rem = idx & 32767;
  int kg  = rem >> 10;
  int n   = rem & 1023;
  const float* Wh = dir ? Whb : Whf;
  unsigned v[4];
#pragma unroll
  for (int j = 0; j < 4; ++j) {
    int k = kg*8 + 2*j;
    float lo = Wh[(size_t)k*1024 + n];
    float hi = Wh[(size_t)(k+1)*1024 + n];
    v[j] = bf16r(lo) | (bf16r(hi) << 16);
  }
  whp4[idx] = make_uint4(v[0], v[1], v[2], v[3]);
}

// ---------------------------------------------------------------------------
// B-pack into MFMA fragment-native bf16 layout:
// Bp[((kc*Ng + g)*64 + lane)*8 + j] = B[k = kc*32+(lane>>4)*8+j][n = g*16+(lane&15)]
// where B[k][n] = trans ? W[n][k] : W[k][n];  k >= Ksrc -> 0 (zero pad)
// ---------------------------------------------------------------------------
__global__ __launch_bounds__(256)
void packB_k(const float* __restrict__ W, short* __restrict__ Bp,
             int KC, int Ng, int Ksrc, int N, int trans)
{
  int idx = blockIdx.x*256 + threadIdx.x;
  if (idx >= KC*Ng*64) return;
  int lane = idx & 63;
  int g    = (idx >> 6) % Ng;
  int kc   = idx / (64*Ng);
  int n = g*16 + (lane & 15);
  int kb = kc*32 + ((lane >> 4) << 3);
  unsigned o[4];
#pragma unroll
  for (int jj = 0; jj < 4; ++jj) {
    int k0 = kb + 2*jj;
    float v0 = (k0   < Ksrc) ? (trans ? W[(size_t)n*Ksrc + k0]   : W[(size_t)(k0)*N + n])   : 0.f;
    float v1 = (k0+1 < Ksrc) ? (trans ? W[(size_t)n*Ksrc + k0+1] : W[(size_t)(k0+1)*N + n]) : 0.f;
    o[jj] = bf16r(v0) | (bf16r(v1) << 16);
  }
  *(uint4*)(Bp + (size_t)idx*8) = make_uint4(o[0], o[1], o[2], o[3]);
}

// ---------------------------------------------------------------------------
// A-pack of image: Ap[((mt*20 + kc)*64 + lane)*8 + j] = image[b][c][p]
// row = mt*16+(lane&15) = b*150+p ; c = kc*32+(lane>>4)*8+j  (CIN=640)
// ---------------------------------------------------------------------------
__global__ __launch_bounds__(256)
void packImg_k(const float* __restrict__ image, short* __restrict__ Ap)
{
  int idx = blockIdx.x*256 + threadIdx.x;   // 600*20*64
  int lane = idx & 63;
  int kc   = (idx >> 6) % 20;
  int mt   = idx / 1280;
  int row = mt*16 + (lane & 15);
  int b = row / 150, p = row % 150;
  int cb = kc*32 + ((lane >> 4) << 3);
  unsigned o[4];
#pragma unroll
  for (int jj = 0; jj < 4; ++jj) {
    float v0 = image[((size_t)b*640 + cb + 2*jj    )*150 + p];
    float v1 = image[((size_t)b*640 + cb + 2*jj + 1)*150 + p];
    o[jj] = bf16r(v0) | (bf16r(v1) << 16);
  }
  *(uint4*)(Ap + (size_t)idx*8) = make_uint4(o[0], o[1], o[2], o[3]);
}

// ---------------------------------------------------------------------------
// A-pack of gathered embeddings: rows (b,s) 0..1919, K=300 padded to 320
// ---------------------------------------------------------------------------
__global__ __launch_bounds__(256)
void packEmb_k(const float* __restrict__ embedW, const int* __restrict__ ques,
               short* __restrict__ Ap)
{
  int idx = blockIdx.x*256 + threadIdx.x;   // 120*10*64
  int lane = idx & 63;
  int kc   = (idx >> 6) % 10;
  int mt   = idx / 640;
  int row = mt*16 + (lane & 15);
  int q = ques[row];
  int kb = kc*32 + ((lane >> 4) << 3);
  unsigned o[4];
#pragma unroll
  for (int jj = 0; jj < 4; ++jj) {
    int k0 = kb + 2*jj;
    float v0 = (k0   < 300) ? embedW[(size_t)q*300 + k0]   : 0.f;
    float v1 = (k0+1 < 300) ? embedW[(size_t)q*300 + k0+1] : 0.f;
    o[jj] = bf16r(v0) | (bf16r(v1) << 16);
  }
  *(uint4*)(Ap + (size_t)idx*8) = make_uint4(o[0], o[1], o[2], o[3]);
}

// ---------------------------------------------------------------------------
// MFMA GEMM: C[M][N] = act(Apack @ Bpack + bias)
// block = 4 waves; wave = 16 rows (mtile) x 64 cols (4 16x16 frags).
// K-loop: pure register MFMA, direct global dwordx4 frag loads, no barriers.
// mode 0: fp32 row-major out; mode 1: bf16 A-pack out (KCout = N/32).
// M mult of 64, N mult of 64.
// ---------------------------------------------------------------------------
__global__ __launch_bounds__(256)
void gemmM_k(const short* __restrict__ Ap, const short* __restrict__ Bp,
             const float* __restrict__ bias, void* __restrict__ Cout,
             int KC, int Ng, int N, int mode, int act, int KCout)
{
  __shared__ float lds[4][16][68];
  const int tid = threadIdx.x, lane = tid & 63, w = tid >> 6;
  const int mt = blockIdx.y*4 + w;
  const int ncol0 = blockIdx.x*64;
  const short* Abase = Ap + (((size_t)mt*KC) << 9) + lane*8;
  const short* Bbase = Bp + (((size_t)blockIdx.x*4) << 9) + lane*8;
  f32x4 acc0 = {0.f,0.f,0.f,0.f}, acc1 = acc0, acc2 = acc0, acc3 = acc0;
#pragma unroll 2
  for (int kc = 0; kc < KC; ++kc) {
    frag a = *(const frag*)(Abase + ((size_t)kc << 9));
    const short* bk = Bbase + (((size_t)kc*Ng) << 9);
    frag b0 = *(const frag*)(bk);
    frag b1 = *(const frag*)(bk + 512);
    frag b2 = *(const frag*)(bk + 1024);
    frag b3 = *(const frag*)(bk + 1536);
    acc0 = __builtin_amdgcn_mfma_f32_16x16x32_bf16(a, b0, acc0, 0, 0, 0);
    acc1 = __builtin_amdgcn_mfma_f32_16x16x32_bf16(a, b1, acc1, 0, 0, 0);
    acc2 = __builtin_amdgcn_mfma_f32_16x16x32_bf16(a, b2, acc2, 0, 0, 0);
    acc3 = __builtin_amdgcn_mfma_f32_16x16x32_bf16(a, b3, acc3, 0, 0, 0);
  }
  // C/D frag: col = lane&15, row = (lane>>4)*4 + reg   [m89-verified]
  {
    int colb = lane & 15, rowb = (lane >> 4)*4;
#pragma unroll
    for (int r = 0; r < 4; ++r) {
      lds[w][rowb+r][ 0+colb] = acc0[r];
      lds[w][rowb+r][16+colb] = acc1[r];
      lds[w][rowb+r][32+colb] = acc2[r];
      lds[w][rowb+r][48+colb] = acc3[r];
    }
  }
  __syncthreads();
  if (mode == 0) {
    float* C = (float*)Cout;
    int mloc = lane >> 2, q4 = lane & 3;
    size_t rowoff = (size_t)(mt*16 + mloc)*N + ncol0 + q4*16;
#pragma unroll
    for (int i = 0; i < 4; ++i) {
      float4 v = *(float4*)&lds[w][mloc][q4*16 + i*4];
      const float* bp = bias + ncol0 + q4*16 + i*4;
      v.x += bp[0]; v.y += bp[1]; v.z += bp[2]; v.w += bp[3];
      if (act) { v.x = elu_(v.x); v.y = elu_(v.y); v.z = elu_(v.z); v.w = elu_(v.w); }
      *(float4*)&C[rowoff + i*4] = v;
    }
  } else {
    short* C = (short*)Cout;
    int m = lane & 15, qb = (lane >> 4)*8;
#pragma unroll
    for (int h = 0; h < 2; ++h) {
      int nl = h*32 + qb;
      unsigned o[4];
#pragma unroll
      for (int jj = 0; jj < 4; ++jj) {
        float v0 = lds[w][m][nl + 2*jj]     + bias[ncol0 + nl + 2*jj];
        float v1 = lds[w][m][nl + 2*jj + 1] + bias[ncol0 + nl + 2*jj + 1];
        if (act) { v0 = elu_(v0); v1 = elu_(v1); }
        o[jj] = bf16r(v0) | (bf16r(v1) << 16);
      }
      *(uint4*)(C + (((size_t)mt*KCout + (ncol0 >> 5) + h) << 9) + lane*8)
          = make_uint4(o[0], o[1], o[2], o[3]);
    }
  }
}

// ---------------------------------------------------------------------------
// 64-row batch GEMM, K-split across waves (latency-optimized) — t-loop GEMMs
// ---------------------------------------------------------------------------
__global__ __launch_bounds__(512)
void gemm64b_k(const float* __restrict__ A1, long zA1, int K1log,
               const float* __restrict__ A2, int K2,
               const float* __restrict__ B, long zB,
               const float* __restrict__ bias, int zbias,
               float* __restrict__ C, long zC, int N, int act)
{
  const int K1 = 1 << K1log;
  const int Kt = K1 + K2;
  __shared__ __align__(16) float As[8][1024];
  __shared__ float part[8][8][64];
  const int tid = threadIdx.x;
  const int z = blockIdx.z;
  const int r0 = blockIdx.y*8;

  {
    const float* a1 = A1 + (size_t)z*zA1;
    const int nf4 = (8*K1) >> 2;
    for (int e4 = tid; e4 < nf4; e4 += 512) {
      int r = e4 >> (K1log-2);
      int k4 = (e4 & ((K1>>2)-1)) << 2;
      *(float4*)&As[r][k4] = *(const float4*)&a1[(size_t)(r0+r)*K1 + k4];
    }
    if (K2 > 0) {  // K2 == 512
      for (int e4 = tid; e4 < 1024; e4 += 512) {
        int r = e4 >> 7;
        int k4 = (e4 & 127) << 2;
        *(float4*)&As[r][K1+k4] = *(const float4*)&A2[(size_t)(r0+r)*512 + k4];
      }
    }
  }
  __syncthreads();

  const int lane = tid & 63, w = tid >> 6;
  const int n = blockIdx.x*64 + lane;
  const bool nv = n < N;
  const int kseg = Kt >> 3;
  const int k0 = w*kseg;
  const float* Bp = B + (size_t)z*zB + (size_t)k0*N + (nv ? n : 0);
  float acc[8] = {0,0,0,0,0,0,0,0};
#pragma unroll 8
  for (int kk = 0; kk < kseg; ++kk) {
    float bv = nv ? Bp[(size_t)kk*N] : 0.f;
    int k = k0 + kk;
#pragma unroll
    for (int r = 0; r < 8; ++r) acc[r] += As[r][k]*bv;
  }
#pragma unroll
  for (int r = 0; r < 8; ++r) part[w][r][lane] = acc[r];
  __syncthreads();
  {
    int r = tid >> 6, c = tid & 63;
    int nn = blockIdx.x*64 + c;
    if (nn < N) {
      float s = 0.f;
#pragma unroll
      for (int w2 = 0; w2 < 8; ++w2) s += part[w2][r][c];
      s += bias ? bias[(size_t)z*zbias + nn] : 0.f;
      if (act == 1) s = elu_(s);
      C[(size_t)z*zC + (size_t)(r0+r)*N + nn] = s;
    }
  }
}

// ---------------------------------------------------------------------------
// bidirectional masked LSTM; 128 blocks = (dir, batch); Wh as uint4 bf16-pairs
// ---------------------------------------------------------------------------
__global__ __launch_bounds__(1024)
void lstm4_k(const float* __restrict__ xWf, const float* __restrict__ xWb,
             const uint4* __restrict__ whp4,
             const int* __restrict__ qlen, float* __restrict__ lstm_out,
             float* __restrict__ qout)
{
  int dir = blockIdx.x >> 6;
  int b   = blockIdx.x & 63;
  const float* xW = dir ? xWb : xWf;
  const uint4* Wp = whp4 + (size_t)dir*32768 + threadIdx.x;
  __shared__ __align__(16) float hl[256];
  __shared__ __align__(16) float cl[256];
  __shared__ float zl[1024];
  int tid = threadIdx.x;
  if (tid < 256) { hl[tid] = 0.f; cl[tid] = 0.f; }
  int len = qlen[b];
  for (int ss = 0; ss < 30; ++ss) {
    int s = dir ? (29-ss) : ss;
    __syncthreads();           // h/c ready
    float z = xW[((size_t)b*30 + s)*1024 + tid];
#pragma unroll 4
    for (int kg = 0; kg < 32; ++kg) {
      uint4 w = Wp[(size_t)kg*1024];
      float4 ha = *(const float4*)&hl[kg*8];
      float4 hb = *(const float4*)&hl[kg*8+4];
      z += ha.x*blo(w.x) + ha.y*bhi(w.x) + ha.z*blo(w.y) + ha.w*bhi(w.y)
         + hb.x*blo(w.z) + hb.y*bhi(w.z) + hb.z*blo(w.w) + hb.w*bhi(w.w);
    }
    zl[tid] = z;
    __syncthreads();
    if (tid < 256) {
      float iv = zl[tid], fv = zl[256+tid], gv = zl[512+tid], ov = zl[768+tid];
      float cn = sigm_(fv)*cl[tid] + sigm_(iv)*tanh_(gv);
      float hn = sigm_(ov)*tanh_(cn);
      bool m = s < len;
      lstm_out[((size_t)b*30 + s)*512 + dir*256 + tid] = m ? hn : 0.f;
      if (m) { hl[tid] = hn; cl[tid] = cn; }
    }
  }
  __syncthreads();
  if (tid < 256) qout[(size_t)b*512 + dir*256 + tid] = hl[tid];
}

// ---------------------------------------------------------------------------
// fused kc + attn: w[9]+entropy from u; attention context -> cprev
// ---------------------------------------------------------------------------
__global__ __launch_bounds__(256)
void kcattn_k(const float* __restrict__ u, const float* __restrict__ Wmod,
              const float* __restrict__ lstm_out, const float* __restrict__ W3,
              float* __restrict__ wout, float* __restrict__ imp_part,
              float* __restrict__ cout, int t)
{
  int b = blockIdx.x;
  int lane = threadIdx.x & 63, wave = threadIdx.x >> 6;
  __shared__ float ush[512];
  __shared__ float wl[9];
  __shared__ float sc[32], at[32];
  ush[threadIdx.x]     = u[b*512 + threadIdx.x];
  ush[256+threadIdx.x] = u[b*512 + 256 + threadIdx.x];
  __syncthreads();
  for (int m = wave; m < 9; m += 4) {
    float acc = 0.f;
    for (int k = lane; k < 512; k += 64) acc += ush[k]*Wmod[k*9+m];
#pragma unroll
    for (int off = 32; off; off >>= 1) acc += __shfl_down(acc, off);
    if (lane == 0) wl[m] = acc;
  }
  for (int s = wave; s < 30; s += 4) {
    float acc = 0.f;
    const float* lo = lstm_out + ((size_t)b*30 + s)*512;
    for (int h = lane; h < 512; h += 64) acc += lo[h]*ush[h]*W3[h];
#pragma unroll
    for (int off = 32; off; off >>= 1) acc += __shfl_down(acc, off);
    if (lane == 0) sc[s] = acc;
  }
  __syncthreads();
  if (threadIdx.x == 0) {
    float mx = wl[0];
    for (int m = 1; m < 9; ++m) mx = fmaxf(mx, wl[m]);
    float s = 0.f;
    for (int m = 0; m < 9; ++m) s += fexp(wl[m]-mx);
    float ls = logf(s);
    float ent = 0.f;
    for (int m = 0; m < 9; ++m) {
      float l = wl[m]-mx-ls;
      float w = fexp(l);
      wout[b*9+m] = w;
      ent -= w*l;
    }
    imp_part[t*64+b] = ent;
  }
  if (wave == 1) {
    float v = (lane < 30) ? sc[lane] : -3.4e38f;
    float mx = v;
#pragma unroll
    for (int off = 32; off; off >>= 1) mx = fmaxf(mx, __shfl_xor(mx, off));
    float e = (lane < 30) ? fexp(v-mx) : 0.f;
    float ssum = e;
#pragma unroll
    for (int off = 32; off; off >>= 1) ssum += __shfl_xor(ssum, off);
    if (lane < 30) at[lane] = e/ssum;
  }
  __syncthreads();
  for (int h = threadIdx.x; h < 512; h += 256) {
    float acc = 0.f;
#pragma unroll 6
    for (int s = 0; s < 30; ++s) acc += at[s]*lstm_out[((size_t)b*30 + s)*512 + h];
    cout[b*512+h] = acc;
  }
}

// ---------------------------------------------------------------------------
// fused modules + pooled partials + stack update.
// ---------------------------------------------------------------------------
__global__ __launch_bounds__(256)
void modules_k(const float* __restrict__ imapT, const float* __restrict__ tmap,
               float* __restrict__ stack, const float* __restrict__ pvec,
               const float* __restrict__ swb, const float* __restrict__ c3w,
               const float* __restrict__ c3b, const float* __restrict__ c4w,
               const float* __restrict__ c4b, const float* __restrict__ wmod,
               float* __restrict__ pl67)
{
  int b  = blockIdx.x;
  int pb = blockIdx.y;
  int lane = threadIdx.x & 63, wave = threadIdx.x >> 6;
  __shared__ float pv[8], pd[8], wm[9];
  __shared__ float wpart[4][2][512];
  if (threadIdx.x < 8) pv[threadIdx.x] = pvec[b*8+threadIdx.x];
  if (threadIdx.x >= 64 && threadIdx.x < 73) wm[threadIdx.x-64] = wmod[b*9 + threadIdx.x-64];
  __syncthreads();
  if (threadIdx.x < 8) {
    int l = threadIdx.x;
    pd[l] = (l < 7 ? pv[l+1] : 0.f) + (l == 0 ? pv[0] : 0.f);
  }
  __syncthreads();

  float W[8][6];
#pragma unroll
  for (int m = 0; m < 8; ++m)
#pragma unroll
    for (int i = 0; i < 6; ++i) W[m][i] = swb[m*6+i];
  float W03 = wm[0]+wm[1]+wm[2]+wm[3];
  float W45 = wm[4]+wm[5];

  float acc6[8], acc7[8];
#pragma unroll
  for (int i = 0; i < 8; ++i) { acc6[i] = 0.f; acc7[i] = 0.f; }

  for (int pi = 0; pi < 2; ++pi) {
    int p = pb*8 + wave*2 + pi;
    if (p >= 150) continue;
    const float* st = stack + ((size_t)b*150 + p)*8;
    float a = 0.f, av2 = 0.f;
#pragma unroll
    for (int l = 0; l < 8; ++l) { float v = st[l]; a += v*pv[l]; av2 += v*pd[l]; }
    float part[6] = {0,0,0,0,0,0};
#pragma unroll 2
    for (int i = 0; i < 8; ++i) {
      int d = i*64 + lane;
      float x = imapT[((size_t)b*150 + p)*512 + d];
      float t = tmap[b*512+d];
#pragma unroll
      for (int m = 0; m < 4; ++m) {
        float c1 = W[m][0]*t + W[m][1] + W[m][4] + (W[m][2] + W[m][3]*t)*a;
        float c0 = W[m][1]*t + W[m][5]*t*a;
        part[m] += elu_(c1*x + c0) * c3w[m*512+d];
      }
#pragma unroll
      for (int m = 0; m < 2; ++m) {
        float c1 = W[4+m][0]*t + W[4+m][1] + W[4+m][2]*a + W[4+m][3]*av2
                 + W[4+m][4]*a*av2 + W[4+m][5]*t*(a+av2);
        part[4+m] += elu_(c1*x + W[4+m][1]*t) * c4w[m*512+d];
      }
      float c16 = W[6][0]*t + W[6][1] + W[6][4] + (W[6][2] + W[6][3]*t)*a;
      float c06 = W[6][1]*t + W[6][5]*t*a;
      acc6[i] += elu_(c16*x + c06);
      float c17 = W[7][0]*t + W[7][1] + W[7][2]*a + W[7][3]*av2
                + W[7][4]*a*av2 + W[7][5]*t*(a+av2);
      acc7[i] += elu_(c17*x + W[7][1]*t);
    }
#pragma unroll
    for (int m = 0; m < 6; ++m) {
#pragma unroll
      for (int off = 32; off; off >>= 1) part[m] += __shfl_down(part[m], off);
      part[m] = __shfl(part[m], 0);
    }
    float r3  = wm[0]*(part[0]+c3b[0]) + wm[1]*(part[1]+c3b[1])
              + wm[2]*(part[2]+c3b[2]) + wm[3]*(part[3]+c3b[3]);
    float r45 = wm[4]*(part[4]+c4b[0]) + wm[5]*(part[5]+c4b[1]);
    if (lane < 8) {
      int l = lane;
      size_t idx = ((size_t)b*150 + p)*8 + l;
      stack[idx] = stack[idx]*(1.f - W03*pv[l] - W45*pd[l])
                 + pv[l]*r3 + pd[l]*r45;
    }
  }
#pragma unroll
  for (int i = 0; i < 8; ++i) {
    wpart[wave][0][i*64+lane] = acc6[i];
    wpart[wave][1][i*64+lane] = acc7[i];
  }
  __syncthreads();
  for (int e = threadIdx.x; e < 1024; e += 256) {
    int which = e >> 9, d = e & 511;
    float s = wpart[0][which][d] + wpart[1][which][d]
            + wpart[2][which][d] + wpart[3][which][d];
    atomicAdd(&pl67[(size_t)which*32768 + b*512 + d], s * (1.f/150.f));
  }
}

// ---------------------------------------------------------------------------
// mem blend + pvec update + zero pl67 for next t
// ---------------------------------------------------------------------------
__global__ __launch_bounds__(256)
void update2_k(const float* __restrict__ wmod, float* __restrict__ pvec,
               float* __restrict__ mem, const float* __restrict__ m67,
               float* __restrict__ pl67)
{
  int b = blockIdx.x;
  __shared__ float wsh[9], pls[8], pds[8];
  if (threadIdx.x < 9) wsh[threadIdx.x] = wmod[b*9+threadIdx.x];
  if (threadIdx.x < 8) pls[threadIdx.x] = pvec[b*8+threadIdx.x];
  __syncthreads();
  if (threadIdx.x < 8) {
    int l = threadIdx.x;
    pds[l] = (l < 7 ? pls[l+1] : 0.f) + (l == 0 ? pls[0] : 0.f);
  }
  __syncthreads();
  float WP = wsh[0]+wsh[1]+wsh[2]+wsh[3] + wsh[6] + wsh[8];
  float WD = wsh[4]+wsh[5] + wsh[7];
  float w6v = wsh[6], w7v = wsh[7];
  for (int d = threadIdx.x; d < 512; d += 256) {
    mem[b*512+d] = w6v*m67[b*512+d] + w7v*m67[32768 + b*512+d]
                 + (1.f - w6v - w7v)*mem[b*512+d];
  }
  for (int e = threadIdx.x; e < 1024; e += 256) {
    int which = e >> 9, d = e & 511;
    pl67[(size_t)which*32768 + b*512 + d] = 0.f;
  }
  __syncthreads();
  if (threadIdx.x < 8) pvec[b*8+threadIdx.x] = WP*pls[threadIdx.x] + WD*pds[threadIdx.x];
}

// ---------------------------------------------------------------------------
__global__ __launch_bounds__(256)
void imp_k(const float* __restrict__ part, float* __restrict__ out)
{
  int lane = threadIdx.x & 63, wave = threadIdx.x >> 6;
  float acc = 0.f;
  for (int i = threadIdx.x; i < 576; i += 256) acc += part[i];
#pragma unroll
  for (int off = 32; off; off >>= 1) acc += __shfl_down(acc, off);
  __shared__ float red[4];
  if (lane == 0) red[wave] = acc;
  __syncthreads();
  if (threadIdx.x == 0) out[0] = red[0]+red[1]+red[2]+red[3];
}

// ---------------------------------------------------------------------------
extern "C" void kernel_launch(void* const* d_in, const int* in_sizes, int n_in,
                              void* d_out, int out_size, void* d_ws, size_t ws_size,
                              hipStream_t stream)
{
  (void)in_sizes; (void)n_in; (void)out_size; (void)ws_size;
  const float* image = (const float*)d_in[0];
  const int*   ques  = (const int*)d_in[1];
  const int*   qlen  = (const int*)d_in[2];
  const float* embedW= (const float*)d_in[3];
  const float* Wi_f  = (const float*)d_in[4];
  const float* Wh_f  = (const float*)d_in[5];
  const float* b_f   = (const float*)d_in[6];
  const float* Wi_b  = (const float*)d_in[7];
  const float* Wh_b  = (const float*)d_in[8];
  const float* b_b   = (const float*)d_in[9];
  const float* W1    = (const float*)d_in[10];
  const float* b1    = (const float*)d_in[11];
  const float* W2w   = (const float*)d_in[12];
  const float* W2b   = (const float*)d_in[13];
  const float* W3    = (const float*)d_in[14];
  const float* c0    = (const float*)d_in[15];
  const float* Wmod  = (const float*)d_in[16];
  const float* ic1w  = (const float*)d_in[17];
  const float* ic1b  = (const float*)d_in[18];
  const float* ic2w  = (const float*)d_in[19];
  const float* ic2b  = (const float*)d_in[20];
  const float* i2mw  = (const float*)d_in[21];
  const float* i2mb  = (const float*)d_in[22];
  const float* t2mw  = (const float*)d_in[23];
  const float* t2mb  = (const float*)d_in[24];
  const float* c3ow  = (const float*)d_in[25];
  const float* c3cw  = (const float*)d_in[26];
  const float* c3cb  = (const float*)d_in[27];
  const float* c4ow  = (const float*)d_in[28];
  const float* c4cw  = (const float*)d_in[29];
  const float* c4cb  = (const float*)d_in[30];
  const float* aow   = (const float*)d_in[31];
  const float* ansW  = (const float*)d_in[32];
  const float* ansb  = (const float*)d_in[33];
  const float* o1w   = (const float*)d_in[34];
  const float* o1b   = (const float*)d_in[35];
  const float* o2w   = (const float*)d_in[36];
  const float* o2b   = (const float*)d_in[37];
  float* out = (float*)d_out;
  float* ws  = (float*)d_ws;

  size_t off = 0;
  auto alloc = [&](size_t n){ float* p = ws + off; off += n; return p; };
  // bf16 packed buffers (sizes in float-equivalents, all 16B aligned)
  short* imgP  = (short*)alloc(600ull*20*64*8/2);   // 9600x640 A-pack
  short* X1p   = (short*)alloc(600ull*16*64*8/2);   // 9600x512 A-pack
  short* X2p   = (short*)alloc(600ull*16*64*8/2);
  short* w1p   = (short*)alloc(20*32*64*8/2);
  short* w2p   = (short*)alloc(16*32*64*8/2);
  short* w3p   = (short*)alloc(16*32*64*8/2);
  short* wifp  = (short*)alloc(10*64*64*8/2);
  short* wibp  = (short*)alloc(10*64*64*8/2);
  short* embp  = (short*)alloc(120ull*10*64*8/2);   // 1920x320 A-pack
  float* imapT = alloc(64ull*150*512);
  float* xWfb  = alloc(64ull*30*1024);
  float* xWbb  = alloc(64ull*30*1024);
  float* lout  = alloc(64ull*30*512);
  float* qbuf  = alloc(64*512);
  float* stck  = alloc(64*150*8);
  float* pvec  = alloc(64*8);
  float* memb  = alloc(64*512);
  float* cprev = alloc(64*512);
  float* tmp1a = alloc(9ull*64*512);
  float* ubuf  = alloc(64*512);
  float* wmw   = alloc(64*9);
  float* impp  = alloc(9*64);
  float* swb   = alloc(48);
  float* pl67  = alloc(2*64*512);
  float* m67   = alloc(2*64*512);
  float* tmapb = alloc(64*512);
  float* h1b   = alloc(64*1024);
  uint4* whp4  = (uint4*)alloc(2*32*1024*4);

  init_k<<<320, 256, 0, stream>>>(c0, c3ow, c4ow, aow, stck, pvec, memb, cprev,
                                  swb, pl67);
  pack4_k<<<256, 256, 0, stream>>>(Wh_f, Wh_b, whp4);
  // weight packs (B[k][n] = W[n][k] for conv weights; = W[k][n] for Wi)
  packB_k<<<160, 256, 0, stream>>>(ic1w, w1p, 20, 32, 640, 512, 1);
  packB_k<<<128, 256, 0, stream>>>(ic2w, w2p, 16, 32, 512, 512, 1);
  packB_k<<<128, 256, 0, stream>>>(i2mw, w3p, 16, 32, 512, 512, 1);
  packB_k<<<160, 256, 0, stream>>>(Wi_f, wifp, 10, 64, 300, 1024, 0);
  packB_k<<<160, 256, 0, stream>>>(Wi_b, wibp, 10, 64, 300, 1024, 0);
  packImg_k<<<3000, 256, 0, stream>>>(image, imgP);
  packEmb_k<<<300, 256, 0, stream>>>(embedW, ques, embp);

  // conv chain (MFMA): conv1 elu -> bf16 pack; conv2 -> bf16 pack; conv3 -> fp32
  gemmM_k<<<dim3(8,150), 256, 0, stream>>>(imgP, w1p, ic1b, X1p,   20, 32, 512, 1, 1, 16);
  gemmM_k<<<dim3(8,150), 256, 0, stream>>>(X1p,  w2p, ic2b, X2p,   16, 32, 512, 1, 0, 16);
  gemmM_k<<<dim3(8,150), 256, 0, stream>>>(X2p,  w3p, i2mb, imapT, 16, 32, 512, 0, 0, 0);
  // embed @ Wi + bias (MFMA), both directions
  gemmM_k<<<dim3(16,30), 256, 0, stream>>>(embp, wifp, b_f, xWfb, 10, 64, 1024, 0, 0, 0);
  gemmM_k<<<dim3(16,30), 256, 0, stream>>>(embp, wibp, b_b, xWbb, 10, 64, 1024, 0, 0, 0);

  lstm4_k<<<128, 1024, 0, stream>>>(xWfb, xWbb, whp4, qlen, lout, qbuf);

  // hoisted: tmp1all[t] = q @ W1[t] + b1, all 9 t in one launch
  gemm64b_k<<<dim3(8,8,9), 512, 0, stream>>>(
      qbuf, 0, 9, (const float*)nullptr, 0,
      W1, 262144, b1, 0, tmp1a, 32768, 512, 0);

  for (int t = 0; t < 9; ++t) {
    gemm64b_k<<<dim3(8,8,1), 512, 0, stream>>>(
        tmp1a + (size_t)t*32768, 0, 9, cprev, 512,
        W2w, 0, W2b, 0, ubuf, 0, 512, 0);
    kcattn_k<<<64, 256, 0, stream>>>(ubuf, Wmod, lout, W3, wmw, impp, cprev, t);
    gemm64b_k<<<dim3(8,8,1), 512, 0, stream>>>(
        cprev, 0, 9, (const float*)nullptr, 0,
        t2mw, 0, t2mb, 0, tmapb, 0, 512, 0);
    modules_k<<<dim3(64,19), 256, 0, stream>>>(
        imapT, tmapb, stck, pvec, swb, c3cw, c3cb, c4cw, c4cb, wmw, pl67);
    gemm64b_k<<<dim3(8,8,2), 512, 0, stream>>>(
        pl67, 32768, 9, tmapb, 512,
        ansW, 524288, ansb, 512, m67, 32768, 512, 0);
    update2_k<<<64, 256, 0, stream>>>(wmw, pvec, memb, m67, pl67);
  }

  // h1 = elu([q, mem] @ out1 + b);  logits = h1 @ out2 + b
  gemm64b_k<<<dim3(16,8,1), 512, 0, stream>>>(
      qbuf, 0, 9, memb, 512, o1w, 0, o1b, 0, h1b, 0, 1024, 1);
  gemm64b_k<<<dim3(1,8,1), 512, 0, stream>>>(
      h1b, 0, 10, (const float*)nullptr, 0, o2w, 0, o2b, 0, out, 0, 32, 0);
  imp_k<<<1, 256, 0, stream>>>(impp, out + 2048);
}